// Round 12
// baseline (174.079 us; speedup 1.0000x reference)
//
#include <hip/hip_runtime.h>

#define D 512
#define H 8
#define HD 64
#define NQ 2048
#define NC 4096
#define SPLIT 8
#define CLEN (NC / SPLIT)   // 512 contexts per split chunk
#define NT (CLEN / 32)      // 16 tiles per chunk
#define M0 3.0f             // fixed softmax max: scores provably < 3
#define KP2 136             // K LDS row stride (shorts): 272B, 16B-aligned
#define VP 40               // V LDS row stride (shorts): 80B, 16B-aligned

// tiled-GEMM geometry
#define TBM 128
#define TBN 64
#define TBK 32
#define TPAD 40             // LDS row stride in shorts: 80B, 16B-aligned

typedef __attribute__((ext_vector_type(8))) short short8;
typedef __attribute__((ext_vector_type(4))) short short4v;
typedef __attribute__((ext_vector_type(4))) float float4v;
typedef __attribute__((ext_vector_type(4))) int int4v;

__device__ inline float bf2f(short s) {
    unsigned int u = ((unsigned int)(unsigned short)s) << 16;
    return __builtin_bit_cast(float, u);
}
__device__ inline short f2bf(float f) {
    unsigned int u = __builtin_bit_cast(unsigned int, f);
    u = (u + 0x7FFF + ((u >> 16) & 1)) >> 16;   // round-to-nearest-even
    return (short)u;
}
// pack two f32 -> one dword of 2 bf16 (RNE, same rounding as f2bf)
__device__ inline int cvtpk(float a, float b) {
    int w;
    asm("v_cvt_pk_bf16_f32 %0, %1, %2" : "=v"(w) : "v"(a), "v"(b));
    return w;
}

// ---------------------------------------------------------------------------
// Cast f32 -> bf16, ALL 6 tensors (fallback path only). Grid 4096 x 256.
// ---------------------------------------------------------------------------
__global__ __launch_bounds__(256) void cast_all(
    const float* __restrict__ s0, const float* __restrict__ s1,
    const float* __restrict__ s2, const float* __restrict__ s3,
    const float* __restrict__ s4, const float* __restrict__ s5,
    short* __restrict__ dst)
{
    int i = blockIdx.x * 256 + threadIdx.x;
    const float* src; int off;
    if      (i < 262144) { src = s0; off = i; }
    else if (i < 786432) { src = s1; off = i - 262144; }
    else if (i < 851968) { src = s2; off = i - 786432; }
    else if (i < 917504) { src = s3; off = i - 851968; }
    else if (i < 983040) { src = s4; off = i - 917504; }
    else                 { src = s5; off = i - 983040; }
    float4v v = ((const float4v*)src)[off];
    short4v o;
    o.x = f2bf(v.x); o.y = f2bf(v.y); o.z = f2bf(v.z); o.w = f2bf(v.w);
    ((short4v*)dst)[i] = o;
}

// ---------------------------------------------------------------------------
// Cast f32 -> bf16, WEIGHTS ONLY (main path; X-cast fused into qkv staging).
// dst = contiguous Wq|Wk|Wv|Wo bf16 region. Grid 1024 x 256 (262144 float4).
// ---------------------------------------------------------------------------
__global__ __launch_bounds__(256) void cast_w(
    const float* __restrict__ s0, const float* __restrict__ s1,
    const float* __restrict__ s2, const float* __restrict__ s3,
    short* __restrict__ dst)
{
    int i = blockIdx.x * 256 + threadIdx.x;      // < 262144
    const float* src; int off;
    if      (i < 65536)  { src = s0; off = i; }
    else if (i < 131072) { src = s1; off = i - 65536; }
    else if (i < 196608) { src = s2; off = i - 131072; }
    else                 { src = s3; off = i - 196608; }
    float4v v = ((const float4v*)src)[off];
    short4v o;
    o.x = f2bf(v.x); o.y = f2bf(v.y); o.z = f2bf(v.z); o.w = f2bf(v.w);
    ((short4v*)dst)[i] = o;
}

// ---------------------------------------------------------------------------
// GEMM: out[M x D] = X @ W^T + bias. Wave computes 16x64 (fallback path).
// ---------------------------------------------------------------------------
__global__ __launch_bounds__(256) void gemm_bt_bias(
    const short* __restrict__ X, const short* __restrict__ W,
    const float* __restrict__ bias, short* __restrict__ out, int M)
{
    int wave = threadIdx.x >> 6, lane = threadIdx.x & 63;
    int gt = blockIdx.x * 4 + wave;
    int tm = gt >> 3;
    int tg = gt & 7;
    if (tm >= (M >> 4)) return;
    int l15 = lane & 15, quad = lane >> 4;
    const short* xp = X + (tm * 16 + l15) * D + quad * 8;
    const short* wp = W + (tg * 64 + l15) * D + quad * 8;
    float4v a0 = {0,0,0,0}, a1 = {0,0,0,0}, a2 = {0,0,0,0}, a3 = {0,0,0,0};
#pragma unroll
    for (int k = 0; k < D; k += 32) {
        short8 a  = *(const short8*)(xp + k);
        short8 b0 = *(const short8*)(wp + k);
        short8 b1 = *(const short8*)(wp + 16 * D + k);
        short8 b2 = *(const short8*)(wp + 32 * D + k);
        short8 b3 = *(const short8*)(wp + 48 * D + k);
        a0 = __builtin_amdgcn_mfma_f32_16x16x32_bf16(a, b0, a0, 0, 0, 0);
        a1 = __builtin_amdgcn_mfma_f32_16x16x32_bf16(a, b1, a1, 0, 0, 0);
        a2 = __builtin_amdgcn_mfma_f32_16x16x32_bf16(a, b2, a2, 0, 0, 0);
        a3 = __builtin_amdgcn_mfma_f32_16x16x32_bf16(a, b3, a3, 0, 0, 0);
    }
    int orow = tm * 16 + quad * 4;
    float4v accs[4] = {a0, a1, a2, a3};
#pragma unroll
    for (int j = 0; j < 4; j++) {
        int col = tg * 64 + j * 16 + l15;
        float bv = bias[col];
#pragma unroll
        for (int r = 0; r < 4; r++)
            out[(orow + r) * D + col] = f2bf(accs[j][r] + bv);
    }
}

// ---------------------------------------------------------------------------
// TILED Q+K+V projection GEMM with FUSED X-cast: A operand read directly
// from f32 activations and converted in staging regs via v_cvt_pk_bf16_f32
// (RNE, bit-identical to the old cast_all+bf16-read path). Pipeline skeleton
// identical to the round-10/11 PASSED gemm_qkv_tiled.
// Grid 640: blk 0..127 Q | 128..383 K | 384..639 V(transposed+rho epilogue).
// ---------------------------------------------------------------------------
__global__ __launch_bounds__(256) void gemm_qkv_tiled_f32(
    const float* __restrict__ Xqf, const float* __restrict__ Xcf,
    const short* __restrict__ Wq, const short* __restrict__ Wk,
    const short* __restrict__ Wv,
    const float* __restrict__ bq, const float* __restrict__ bk,
    const float* __restrict__ bv,
    short* __restrict__ Qout, short* __restrict__ Kout,
    short* __restrict__ VoutT)
{
    __shared__ __align__(16) short Ab[2][TBM * TPAD];   // 20480 B
    __shared__ __align__(16) short Bb[2][TBN * TPAD];   // 10240 B

    int tid = threadIdx.x;
    int wave = tid >> 6, lane = tid & 63;
    int quad = lane >> 4, l15 = lane & 15;

    int blk = blockIdx.x;
    const float* Xf;
    const short* W;
    const float* bias;
    short* outp;
    int bm, bn, vmode;
    if (blk < 128) {                       // Q (M = NQ)
        Xf = Xqf; W = Wq; bias = bq; outp = Qout; vmode = 0;
        bm = (blk >> 3) * TBM; bn = (blk & 7) * TBN;
    } else if (blk < 384) {                // K (M = NC)
        int b = blk - 128;
        Xf = Xcf; W = Wk; bias = bk; outp = Kout; vmode = 0;
        bm = (b >> 3) * TBM; bn = (b & 7) * TBN;
    } else {                               // V (M = NC, transposed epilogue)
        int b = blk - 384;
        Xf = Xcf; W = Wv; bias = bv; outp = VoutT; vmode = 1;
        bm = (b >> 3) * TBM; bn = (b & 7) * TBN;
    }

    // staging maps: A 128x32 (16 floats -> 16 bf16 per thread),
    //               B 64x32 (1 short8 per thread, bf16 weights)
    int ar = tid >> 1, ac = (tid & 1) * 16;
    int br = tid >> 2, bc = (tid & 3) * 8;
    const float* ag = Xf + (size_t)(bm + ar) * D + ac;
    const short* bg = W + (size_t)(bn + br) * D + bc;
    short* aw0 = &Ab[0][ar * TPAD + ac];
    short* aw1 = &Ab[1][ar * TPAD + ac];
    short* bw0 = &Bb[0][br * TPAD + bc];
    short* bw1 = &Bb[1][br * TPAD + bc];

    short8 ra0, ra1, rb;

#define GLOAD(ks) {                                                            \
        const float* ap_ = ag + (ks) * TBK;                                    \
        float4v f0 = *(const float4v*)(ap_);                                   \
        float4v f1 = *(const float4v*)(ap_ + 4);                               \
        float4v f2 = *(const float4v*)(ap_ + 8);                               \
        float4v f3 = *(const float4v*)(ap_ + 12);                              \
        int4v w0, w1;                                                          \
        w0.x = cvtpk(f0.x, f0.y); w0.y = cvtpk(f0.z, f0.w);                    \
        w0.z = cvtpk(f1.x, f1.y); w0.w = cvtpk(f1.z, f1.w);                    \
        w1.x = cvtpk(f2.x, f2.y); w1.y = cvtpk(f2.z, f2.w);                    \
        w1.z = cvtpk(f3.x, f3.y); w1.w = cvtpk(f3.z, f3.w);                    \
        ra0 = __builtin_bit_cast(short8, w0);                                  \
        ra1 = __builtin_bit_cast(short8, w1);                                  \
        rb  = *(const short8*)(bg + (ks) * TBK); }
#define GDSW0 { *(short8*)aw0 = ra0; *(short8*)(aw0 + 8) = ra1;                \
                *(short8*)bw0 = rb; }
#define GDSW1 { *(short8*)aw1 = ra0; *(short8*)(aw1 + 8) = ra1;                \
                *(short8*)bw1 = rb; }

    float4v c00 = {0,0,0,0}, c01 = {0,0,0,0}, c02 = {0,0,0,0}, c03 = {0,0,0,0};
    float4v c10 = {0,0,0,0}, c11 = {0,0,0,0}, c12 = {0,0,0,0}, c13 = {0,0,0,0};

#define GCOMP(B)                                                               \
    {                                                                          \
        const short* abase = &Ab[B][(wave * 32 + l15) * TPAD + quad * 8];      \
        const short* bbase = &Bb[B][l15 * TPAD + quad * 8];                    \
        short8 a0 = *(const short8*)(abase);                                   \
        short8 a1 = *(const short8*)(abase + 16 * TPAD);                       \
        short8 b0 = *(const short8*)(bbase);                                   \
        short8 b1 = *(const short8*)(bbase + 16 * TPAD);                       \
        short8 b2 = *(const short8*)(bbase + 32 * TPAD);                       \
        short8 b3 = *(const short8*)(bbase + 48 * TPAD);                       \
        c00 = __builtin_amdgcn_mfma_f32_16x16x32_bf16(a0, b0, c00, 0, 0, 0);   \
        c01 = __builtin_amdgcn_mfma_f32_16x16x32_bf16(a0, b1, c01, 0, 0, 0);   \
        c02 = __builtin_amdgcn_mfma_f32_16x16x32_bf16(a0, b2, c02, 0, 0, 0);   \
        c03 = __builtin_amdgcn_mfma_f32_16x16x32_bf16(a0, b3, c03, 0, 0, 0);   \
        c10 = __builtin_amdgcn_mfma_f32_16x16x32_bf16(a1, b0, c10, 0, 0, 0);   \
        c11 = __builtin_amdgcn_mfma_f32_16x16x32_bf16(a1, b1, c11, 0, 0, 0);   \
        c12 = __builtin_amdgcn_mfma_f32_16x16x32_bf16(a1, b2, c12, 0, 0, 0);   \
        c13 = __builtin_amdgcn_mfma_f32_16x16x32_bf16(a1, b3, c13, 0, 0, 0);   \
    }

    GLOAD(0);
    GDSW0;
    GLOAD(1);
    __syncthreads();

    for (int t = 0; t < 14; t += 2) {
        GDSW1;
        GLOAD(t + 2);
        GCOMP(0);
        __syncthreads();
        GDSW0;
        GLOAD(t + 3);
        GCOMP(1);
        __syncthreads();
    }
    GDSW1;
    GCOMP(0);
    __syncthreads();
    GCOMP(1);

#undef GLOAD
#undef GDSW0
#undef GDSW1
#undef GCOMP

    float4v accs[2][4] = {{c00, c01, c02, c03}, {c10, c11, c12, c13}};
    if (vmode == 0) {
#pragma unroll
        for (int mf = 0; mf < 2; mf++) {
            int orow = bm + wave * 32 + mf * 16 + quad * 4;
#pragma unroll
            for (int nf = 0; nf < 4; nf++) {
                int col = bn + nf * 16 + l15;
                float bb_ = bias[col];
#pragma unroll
                for (int r = 0; r < 4; r++)
                    outp[(size_t)(orow + r) * D + col] = f2bf(accs[mf][nf][r] + bb_);
            }
        }
    } else {
#pragma unroll
        for (int mf = 0; mf < 2; mf++) {
            int orow = bm + wave * 32 + mf * 16 + quad * 4;
            int a = (orow & 31) >> 2;
            int posb = (a < 4) ? (8 * a) : (8 * (a - 4) + 4);
            int cp = (orow & ~31) + posb;
#pragma unroll
            for (int nf = 0; nf < 4; nf++) {
                int col = bn + nf * 16 + l15;
                float bb_ = bias[col];
                short4v o;
#pragma unroll
                for (int r = 0; r < 4; r++) o[r] = f2bf(accs[mf][nf][r] + bb_);
                *(short4v*)(outp + (size_t)col * NC + cp) = o;
            }
        }
    }
}

// ---------------------------------------------------------------------------
// TILED output projection: Xf = Att @ Wo^T + bo + resid (f32 out).
// Round-11 PASSED kernel, unchanged. Grid 128.
// ---------------------------------------------------------------------------
__global__ __launch_bounds__(256) void gemm_out_tiled(
    const short* __restrict__ X, const short* __restrict__ W,
    const float* __restrict__ bias, const float* __restrict__ resid,
    float* __restrict__ out)
{
    __shared__ __align__(16) short Ab[2][TBM * TPAD];   // 20480 B
    __shared__ __align__(16) short Bb[2][TBN * TPAD];   // 10240 B

    int tid = threadIdx.x;
    int wave = tid >> 6, lane = tid & 63;
    int quad = lane >> 4, l15 = lane & 15;

    int blk = blockIdx.x;
    int bm = (blk >> 3) * TBM, bn = (blk & 7) * TBN;

    int ar = tid >> 1, ac = (tid & 1) * 16;
    int br = tid >> 2, bc = (tid & 3) * 8;
    const short* ag = X + (size_t)(bm + ar) * D + ac;
    const short* bg = W + (size_t)(bn + br) * D + bc;
    short* aw0 = &Ab[0][ar * TPAD + ac];
    short* aw1 = &Ab[1][ar * TPAD + ac];
    short* bw0 = &Bb[0][br * TPAD + bc];
    short* bw1 = &Bb[1][br * TPAD + bc];

    short8 ra0, ra1, rb;

#define GLOAD(ks) { const short* ap_ = ag + (ks) * TBK;                        \
        ra0 = *(const short8*)(ap_);                                           \
        ra1 = *(const short8*)(ap_ + 8);                                       \
        rb  = *(const short8*)(bg + (ks) * TBK); }
#define GDSW0 { *(short8*)aw0 = ra0; *(short8*)(aw0 + 8) = ra1;                \
                *(short8*)bw0 = rb; }
#define GDSW1 { *(short8*)aw1 = ra0; *(short8*)(aw1 + 8) = ra1;                \
                *(short8*)bw1 = rb; }

    float4v c00 = {0,0,0,0}, c01 = {0,0,0,0}, c02 = {0,0,0,0}, c03 = {0,0,0,0};
    float4v c10 = {0,0,0,0}, c11 = {0,0,0,0}, c12 = {0,0,0,0}, c13 = {0,0,0,0};

#define GCOMP(B)                                                               \
    {                                                                          \
        const short* abase = &Ab[B][(wave * 32 + l15) * TPAD + quad * 8];      \
        const short* bbase = &Bb[B][l15 * TPAD + quad * 8];                    \
        short8 a0 = *(const short8*)(abase);                                   \
        short8 a1 = *(const short8*)(abase + 16 * TPAD);                       \
        short8 b0 = *(const short8*)(bbase);                                   \
        short8 b1 = *(const short8*)(bbase + 16 * TPAD);                       \
        short8 b2 = *(const short8*)(bbase + 32 * TPAD);                       \
        short8 b3 = *(const short8*)(bbase + 48 * TPAD);                       \
        c00 = __builtin_amdgcn_mfma_f32_16x16x32_bf16(a0, b0, c00, 0, 0, 0);   \
        c01 = __builtin_amdgcn_mfma_f32_16x16x32_bf16(a0, b1, c01, 0, 0, 0);   \
        c02 = __builtin_amdgcn_mfma_f32_16x16x32_bf16(a0, b2, c02, 0, 0, 0);   \
        c03 = __builtin_amdgcn_mfma_f32_16x16x32_bf16(a0, b3, c03, 0, 0, 0);   \
        c10 = __builtin_amdgcn_mfma_f32_16x16x32_bf16(a1, b0, c10, 0, 0, 0);   \
        c11 = __builtin_amdgcn_mfma_f32_16x16x32_bf16(a1, b1, c11, 0, 0, 0);   \
        c12 = __builtin_amdgcn_mfma_f32_16x16x32_bf16(a1, b2, c12, 0, 0, 0);   \
        c13 = __builtin_amdgcn_mfma_f32_16x16x32_bf16(a1, b3, c13, 0, 0, 0);   \
    }

    GLOAD(0);
    GDSW0;
    GLOAD(1);
    __syncthreads();

    for (int t = 0; t < 14; t += 2) {
        GDSW1;
        GLOAD(t + 2);
        GCOMP(0);
        __syncthreads();
        GDSW0;
        GLOAD(t + 3);
        GCOMP(1);
        __syncthreads();
    }
    GDSW1;
    GCOMP(0);
    __syncthreads();
    GCOMP(1);

#undef GLOAD
#undef GDSW0
#undef GDSW1
#undef GCOMP

    float4v accs[2][4] = {{c00, c01, c02, c03}, {c10, c11, c12, c13}};
#pragma unroll
    for (int mf = 0; mf < 2; mf++) {
        int orow = bm + wave * 32 + mf * 16 + quad * 4;
#pragma unroll
        for (int nf = 0; nf < 4; nf++) {
            int col = bn + nf * 16 + l15;
            float bb_ = bias[col];
#pragma unroll
            for (int r = 0; r < 4; r++)
                out[(size_t)(orow + r) * D + col] =
                    accs[mf][nf][r] + bb_ + resid[(size_t)(orow + r) * D + col];
        }
    }
}

// Fallback: naive res GEMM writing f32 (used with separate layernorm_kernel).
__global__ __launch_bounds__(256) void gemm_bt_bias_res_f32(
    const short* __restrict__ X, const short* __restrict__ W,
    const float* __restrict__ bias, const float* __restrict__ resid,
    float* __restrict__ out, int M)
{
    int wave = threadIdx.x >> 6, lane = threadIdx.x & 63;
    int gt = blockIdx.x * 4 + wave;
    int tm = gt >> 3;
    int tg = gt & 7;
    if (tm >= (M >> 4)) return;
    int l15 = lane & 15, quad = lane >> 4;
    const short* xp = X + (tm * 16 + l15) * D + quad * 8;
    const short* wp = W + (tg * 64 + l15) * D + quad * 8;
    float4v a0 = {0,0,0,0}, a1 = {0,0,0,0}, a2 = {0,0,0,0}, a3 = {0,0,0,0};
#pragma unroll
    for (int k = 0; k < D; k += 32) {
        short8 a  = *(const short8*)(xp + k);
        short8 b0 = *(const short8*)(wp + k);
        short8 b1 = *(const short8*)(wp + 16 * D + k);
        short8 b2 = *(const short8*)(wp + 32 * D + k);
        short8 b3 = *(const short8*)(wp + 48 * D + k);
        a0 = __builtin_amdgcn_mfma_f32_16x16x32_bf16(a, b0, a0, 0, 0, 0);
        a1 = __builtin_amdgcn_mfma_f32_16x16x32_bf16(a, b1, a1, 0, 0, 0);
        a2 = __builtin_amdgcn_mfma_f32_16x16x32_bf16(a, b2, a2, 0, 0, 0);
        a3 = __builtin_amdgcn_mfma_f32_16x16x32_bf16(a, b3, a3, 0, 0, 0);
    }
    int orow = tm * 16 + quad * 4;
    float4v accs[4] = {a0, a1, a2, a3};
#pragma unroll
    for (int j = 0; j < 4; j++) {
        int col = tg * 64 + j * 16 + l15;
        float bv = bias[col];
#pragma unroll
        for (int r = 0; r < 4; r++) {
            int q = orow + r;
            out[q * D + col] = accs[j][r] + bv + resid[q * D + col];
        }
    }
}

// ---------------------------------------------------------------------------
// MFMA flash attention v10 = v9 (PASSED at 170us) + XCD-aware 1D grid
// swizzle ONLY: grid 1024, decode s=(d&7)*128+(d>>3) -> (bx,by,bz).
// Bijective (d = (by*32+bx)*8 + bz); all 32 bx-blocks sharing a K/V slab
// satisfy d%8 == bz -> same XCD -> slab (1MB) fetched once per L2.
// Kernel body otherwise byte-identical to v9.
// NOTE: cc-from-global (v7/v8) produced NaN twice — do not reintroduce.
// ---------------------------------------------------------------------------
__global__ __launch_bounds__(256) void attn_mfma_split10(
    const short* __restrict__ Q, const short* __restrict__ K,
    const short* __restrict__ Vp,
    const float* __restrict__ qc, const float* __restrict__ cc,
    const float* __restrict__ log_scale, const float* __restrict__ bph,
    short* __restrict__ Opart, float* __restrict__ Lpart)
{
    __shared__ __align__(16) short Klds[2][32 * KP2];   // 17408 B
    __shared__ __align__(16) short Vlds[2][128 * VP];   // 20480 B
    __shared__ __align__(16) float ccl[512];            //  2048 B (256 ctx)

    int tid = threadIdx.x;
    int wave = tid >> 6, lane = tid & 63;

    // XCD swizzle decode
    int d = blockIdx.x;
    int s = (d & 7) * 128 + (d >> 3);
    int bx = s & 31;
    int by = (s >> 5) & 3;
    int bz = s >> 7;

    int h0 = by * 2;                    // head pair (h0, h0+1)
    int sp = bz;
    int q0 = bx * 64 + wave * 16;
    int quad = lane >> 4, l15 = lane & 15;
    int cbase = sp * CLEN;

    const float LOG2E = 1.4426950408889634f;
    const float escale = 0.125f * LOG2E;
    const float M0L = M0 * LOG2E;
    float ebase = __expf(log_scale[0]);
    float bh0 = ebase * bph[h0] * LOG2E;
    float bh1 = ebase * bph[h0 + 1] * LOG2E;

    const short* qp = Q + (q0 + l15) * D + h0 * HD + quad * 8;
    short8 qa0_0 = *(const short8*)(qp);
    short8 qa1_0 = *(const short8*)(qp + 32);
    short8 qa0_1 = *(const short8*)(qp + 64);
    short8 qa1_1 = *(const short8*)(qp + 96);

    float qx = qc[(q0 + l15) * 2];
    float qy = qc[(q0 + l15) * 2 + 1];

    float lacc0 = 0.f, lacc1 = 0.f;
    float4v O00 = {0,0,0,0}, O01 = {0,0,0,0}, O02 = {0,0,0,0}, O03 = {0,0,0,0};
    float4v O10 = {0,0,0,0}, O11 = {0,0,0,0}, O12 = {0,0,0,0}, O13 = {0,0,0,0};

    int kr_ = tid >> 3, kc_ = tid & 7;
    int vr_ = tid >> 2, vc_ = tid & 3;
    const short* kg  = K + (size_t)h0 * HD + kc_ * 8;            // +(c0+kr_)*D
    const short* vg0 = Vp + (size_t)(h0 * HD + vr_) * NC + vc_ * 8;       // +c0
    const short* vg1 = Vp + (size_t)(h0 * HD + 64 + vr_) * NC + vc_ * 8;  // +c0
    short* kw0a = &Klds[0][kr_ * KP2 + kc_ * 8];
    short* kw1a = &Klds[1][kr_ * KP2 + kc_ * 8];
    short* vw0a = &Vlds[0][vr_ * VP + vc_ * 8];
    short* vw0b = &Vlds[0][(64 + vr_) * VP + vc_ * 8];
    short* vw1a = &Vlds[1][vr_ * VP + vc_ * 8];
    short* vw1b = &Vlds[1][(64 + vr_) * VP + vc_ * 8];

    short8 rka, rkb, rva, rvb;   // staged regs for the next tile

#define LOADR(c0_)                                                             \
    {                                                                          \
        const short* kp_ = kg + (size_t)((c0_) + kr_) * D;                     \
        rka = *(const short8*)(kp_);                                           \
        rkb = *(const short8*)(kp_ + 64);                                      \
        rva = *(const short8*)(vg0 + (c0_));                                   \
        rvb = *(const short8*)(vg1 + (c0_));                                   \
    }

#define DSW0 { *(short8*)kw0a = rka; *(short8*)(kw0a + 64) = rkb;              \
               *(short8*)vw0a = rva; *(short8*)vw0b = rvb; }
#define DSW1 { *(short8*)kw1a = rka; *(short8*)(kw1a + 64) = rkb;              \
               *(short8*)vw1a = rva; *(short8*)vw1b = rvb; }

    const float2* ccp = (const float2*)ccl;

#define HEAD(hoff, QA0, QA1, BH, LACC, OA, OB, OC, OD)                         \
    {                                                                          \
        short8 k00 = *(const short8*)(kb + l15 * KP2 + (hoff) + quad * 8);     \
        short8 k01 = *(const short8*)(kb + l15 * KP2 + (hoff) + 32 + quad * 8);\
        short8 k10 = *(const short8*)(kb + (16 + l15) * KP2 + (hoff) + quad * 8);\
        short8 k11 = *(const short8*)(kb + (16 + l15) * KP2 + (hoff) + 32 + quad * 8);\
        float4v s0 = {0,0,0,0}, s1 = {0,0,0,0};                                \
        s0 = __builtin_amdgcn_mfma_f32_16x16x32_bf16(k00, QA0, s0, 0, 0, 0);   \
        s0 = __builtin_amdgcn_mfma_f32_16x16x32_bf16(k01, QA1, s0, 0, 0, 0);   \
        s1 = __builtin_amdgcn_mfma_f32_16x16x32_bf16(k10, QA0, s1, 0, 0, 0);   \
        s1 = __builtin_amdgcn_mfma_f32_16x16x32_bf16(k11, QA1, s1, 0, 0, 0);   \
        short8 v0 = *(const short8*)(vb + ((hoff) / 64 * 64 + l15) * VP + quad * 8);       \
        short8 v1 = *(const short8*)(vb + ((hoff) / 64 * 64 + 16 + l15) * VP + quad * 8);  \
        short8 v2 = *(const short8*)(vb + ((hoff) / 64 * 64 + 32 + l15) * VP + quad * 8);  \
        short8 v3 = *(const short8*)(vb + ((hoff) / 64 * 64 + 48 + l15) * VP + quad * 8);  \
        float p00 = exp2f(__fmaf_rn(s0[0], escale, __fmaf_rn(-(BH), dA0, -M0L)));\
        float p01 = exp2f(__fmaf_rn(s0[1], escale, __fmaf_rn(-(BH), dA1, -M0L)));\
        float p02 = exp2f(__fmaf_rn(s0[2], escale, __fmaf_rn(-(BH), dA2, -M0L)));\
        float p03 = exp2f(__fmaf_rn(s0[3], escale, __fmaf_rn(-(BH), dA3, -M0L)));\
        float p10 = exp2f(__fmaf_rn(s1[0], escale, __fmaf_rn(-(BH), dB0, -M0L)));\
        float p11 = exp2f(__fmaf_rn(s1[1], escale, __fmaf_rn(-(BH), dB1, -M0L)));\
        float p12 = exp2f(__fmaf_rn(s1[2], escale, __fmaf_rn(-(BH), dB2, -M0L)));\
        float p13 = exp2f(__fmaf_rn(s1[3], escale, __fmaf_rn(-(BH), dB3, -M0L)));\
        LACC += ((p00 + p01) + (p02 + p03)) + ((p10 + p11) + (p12 + p13));     \
        int4v pw;                                                              \
        pw.x = cvtpk(p00, p01); pw.y = cvtpk(p02, p03);                        \
        pw.z = cvtpk(p10, p11); pw.w = cvtpk(p12, p13);                        \
        short8 pa = __builtin_bit_cast(short8, pw);                            \
        OA = __builtin_amdgcn_mfma_f32_16x16x32_bf16(pa, v0, OA, 0, 0, 0);     \
        OB = __builtin_amdgcn_mfma_f32_16x16x32_bf16(pa, v1, OB, 0, 0, 0);     \
        OC = __builtin_amdgcn_mfma_f32_16x16x32_bf16(pa, v2, OC, 0, 0, 0);     \
        OD = __builtin_amdgcn_mfma_f32_16x16x32_bf16(pa, v3, OD, 0, 0, 0);     \
    }

#define COMPUTE_TILE(B, lo)                                                    \
    {                                                                          \
        const short* kb = &Klds[B][0];                                         \
        const short* vb = &Vlds[B][0];                                         \
        float2 ca0 = ccp[(lo) + 4 * quad + 0], cb0 = ccp[(lo) + 16 + 4 * quad + 0];\
        float2 ca1 = ccp[(lo) + 4 * quad + 1], cb1 = ccp[(lo) + 16 + 4 * quad + 1];\
        float2 ca2 = ccp[(lo) + 4 * quad + 2], cb2 = ccp[(lo) + 16 + 4 * quad + 2];\
        float2 ca3 = ccp[(lo) + 4 * quad + 3], cb3 = ccp[(lo) + 16 + 4 * quad + 3];\
        float dx, dy;                                                          \
        dx = qx - ca0.x; dy = qy - ca0.y;                                      \
        float dA0 = __builtin_amdgcn_sqrtf(__fmaf_rn(dx, dx, dy * dy));        \
        dx = qx - ca1.x; dy = qy - ca1.y;                                      \
        float dA1 = __builtin_amdgcn_sqrtf(__fmaf_rn(dx, dx, dy * dy));        \
        dx = qx - ca2.x; dy = qy - ca2.y;                                      \
        float dA2 = __builtin_amdgcn_sqrtf(__fmaf_rn(dx, dx, dy * dy));        \
        dx = qx - ca3.x; dy = qy - ca3.y;                                      \
        float dA3 = __builtin_amdgcn_sqrtf(__fmaf_rn(dx, dx, dy * dy));        \
        dx = qx - cb0.x; dy = qy - cb0.y;                                      \
        float dB0 = __builtin_amdgcn_sqrtf(__fmaf_rn(dx, dx, dy * dy));        \
        dx = qx - cb1.x; dy = qy - cb1.y;                                      \
        float dB1 = __builtin_amdgcn_sqrtf(__fmaf_rn(dx, dx, dy * dy));        \
        dx = qx - cb2.x; dy = qy - cb2.y;                                      \
        float dB2 = __builtin_amdgcn_sqrtf(__fmaf_rn(dx, dx, dy * dy));        \
        dx = qx - cb3.x; dy = qy - cb3.y;                                      \
        float dB3 = __builtin_amdgcn_sqrtf(__fmaf_rn(dx, dx, dy * dy));        \
        HEAD(0,  qa0_0, qa1_0, bh0, lacc0, O00, O01, O02, O03)                 \
        HEAD(64, qa0_1, qa1_1, bh1, lacc1, O10, O11, O12, O13)                 \
    }

    // ---- prologue: cc phase A (256 ctx) -> LDS, tile0 -> buf0, tile1 -> regs
    ((float2*)ccl)[tid] = ((const float2*)cc)[cbase + tid];
    LOADR(cbase);
    DSW0;
    LOADR(cbase + 32);
    __syncthreads();

    // ---- main loop: 16 tiles, 2x-unrolled (static buffer indices) ----
    for (int t = 0; t < NT - 2; t += 2) {
        int c0 = cbase + t * 32;
        if (t == 8) {
            ((float2*)ccl)[tid] = ((const float2*)cc)[cbase + 256 + tid];
            __syncthreads();
        }
        DSW1;
        LOADR(c0 + 64);
        COMPUTE_TILE(0, (t & 7) * 32);
        __syncthreads();
        DSW0;
        LOADR(c0 + 96);
        COMPUTE_TILE(1, (t & 7) * 32 + 32);
        __syncthreads();
    }
    DSW1;
    COMPUTE_TILE(0, 192);   // tile 14, rel (14-8)*32
    __syncthreads();
    COMPUTE_TILE(1, 224);   // tile 15, rel (15-8)*32

#undef LOADR
#undef DSW0
#undef DSW1
#undef HEAD
#undef COMPUTE_TILE

    lacc0 += __shfl_xor(lacc0, 16);
    lacc0 += __shfl_xor(lacc0, 32);
    lacc1 += __shfl_xor(lacc1, 16);
    lacc1 += __shfl_xor(lacc1, 32);

    long base0 = (long)(sp * H + h0) * NQ;
    long base1 = base0 + NQ;
    float4v Oarr0[4] = {O00, O01, O02, O03};
    float4v Oarr1[4] = {O10, O11, O12, O13};
#pragma unroll
    for (int t = 0; t < 4; t++) {
#pragma unroll
        for (int r = 0; r < 4; r++) {
            int q = q0 + quad * 4 + r;
            Opart[(base0 + q) * HD + t * 16 + l15] = f2bf(Oarr0[t][r]);
            Opart[(base1 + q) * HD + t * 16 + l15] = f2bf(Oarr1[t][r]);
        }
    }
    if (lane < 16) {
        Lpart[base0 + q0 + lane] = lacc0;
        Lpart[base1 + q0 + lane] = lacc1;
    }
}

// Plain-sum combine (all splits share fixed max M0) -> bf16 Att.
__global__ __launch_bounds__(256) void attn_combine(
    const short* __restrict__ Opart, const float* __restrict__ Lpart,
    short* __restrict__ Att)
{
    int id = blockIdx.x * 256 + threadIdx.x;   // over H*NQ*HD = 2^20
    int d = id & 63;
    int q = (id >> 6) & (NQ - 1);
    int h = id >> 17;
    float L = 0.f, acc = 0.f;
#pragma unroll
    for (int s = 0; s < SPLIT; s++) {
        long b = (long)(s * H + h) * NQ + q;
        L   += Lpart[b];
        acc += bf2f(Opart[b * HD + d]);
    }
    Att[q * D + h * HD + d] = f2bf(acc / L);
}

// ---------------------------------------------------------------------------
// Fallback single-pass attention (exact online softmax) if ws is too small.
// Expects V row-major [NC][D], unscaled Q.
// ---------------------------------------------------------------------------
__global__ __launch_bounds__(256) void attn_mfma(
    const short* __restrict__ Q, const short* __restrict__ K,
    const short* __restrict__ V,
    const float* __restrict__ qc, const float* __restrict__ cc,
    const float* __restrict__ log_scale, const float* __restrict__ bph,
    short* __restrict__ out)
{
    __shared__ short Vt[HD][48];
    __shared__ short P[4][16][48];
    int wave = threadIdx.x >> 6, lane = threadIdx.x & 63;
    int h = blockIdx.y;
    int q0 = blockIdx.x * 64 + wave * 16;
    int quad = lane >> 4, l15 = lane & 15;
    const float scale = 0.125f;
    float bh = __expf(log_scale[0]) * bph[h];
    const short* qp = Q + (q0 + l15) * D + h * HD + quad * 8;
    short8 qa0 = *(const short8*)(qp);
    short8 qa1 = *(const short8*)(qp + 32);
    float qx[4], qy[4];
#pragma unroll
    for (int r = 0; r < 4; r++) {
        int q = q0 + quad * 4 + r;
        qx[r] = qc[q * 2]; qy[r] = qc[q * 2 + 1];
    }
    float m[4], l[4];
    float4v O[4];
#pragma unroll
    for (int r = 0; r < 4; r++) { m[r] = -1e30f; l[r] = 0.f; }
#pragma unroll
    for (int t = 0; t < 4; t++) O[t] = (float4v){0.f, 0.f, 0.f, 0.f};
    for (int c0 = 0; c0 < NC; c0 += 32) {
        __syncthreads();
        {
            int c = threadIdx.x >> 3;
            int dblk = (threadIdx.x & 7) * 8;
            short8 vv = *(const short8*)(V + (c0 + c) * D + h * HD + dblk);
#pragma unroll
            for (int j = 0; j < 8; j++) Vt[dblk + j][c] = vv[j];
        }
        const short* kp0 = K + (c0 + l15) * D + h * HD + quad * 8;
        const short* kp1 = kp0 + 16 * D;
        short8 kb00 = *(const short8*)(kp0);
        short8 kb01 = *(const short8*)(kp0 + 32);
        short8 kb10 = *(const short8*)(kp1);
        short8 kb11 = *(const short8*)(kp1 + 32);
        float4v s0 = {0,0,0,0}, s1 = {0,0,0,0};
        s0 = __builtin_amdgcn_mfma_f32_16x16x32_bf16(qa0, kb00, s0, 0, 0, 0);
        s0 = __builtin_amdgcn_mfma_f32_16x16x32_bf16(qa1, kb01, s0, 0, 0, 0);
        s1 = __builtin_amdgcn_mfma_f32_16x16x32_bf16(qa0, kb10, s1, 0, 0, 0);
        s1 = __builtin_amdgcn_mfma_f32_16x16x32_bf16(qa1, kb11, s1, 0, 0, 0);
        int cA = c0 + l15, cB = cA + 16;
        float cxA = cc[cA * 2], cyA = cc[cA * 2 + 1];
        float cxB = cc[cB * 2], cyB = cc[cB * 2 + 1];
#pragma unroll
        for (int r = 0; r < 4; r++) {
            float dxA = qx[r] - cxA, dyA = qy[r] - cyA;
            float dxB = qx[r] - cxB, dyB = qy[r] - cyB;
            float v0 = s0[r] * scale - bh * sqrtf(dxA * dxA + dyA * dyA);
            float v1 = s1[r] * scale - bh * sqrtf(dxB * dxB + dyB * dyB);
            float mx = fmaxf(v0, v1);
#pragma unroll
            for (int off = 1; off < 16; off <<= 1) mx = fmaxf(mx, __shfl_xor(mx, off));
            float mnew = fmaxf(m[r], mx);
            float alpha = __expf(m[r] - mnew);
            float p0 = __expf(v0 - mnew);
            float p1 = __expf(v1 - mnew);
            float ps = p0 + p1;
#pragma unroll
            for (int off = 1; off < 16; off <<= 1) ps += __shfl_xor(ps, off);
            l[r] = l[r] * alpha + ps;
            m[r] = mnew;
#pragma unroll
            for (int t = 0; t < 4; t++) O[t][r] *= alpha;
            P[wave][quad * 4 + r][l15]      = f2bf(p0);
            P[wave][quad * 4 + r][16 + l15] = f2bf(p1);
        }
        __syncthreads();
        short8 pa = *(const short8*)(&P[wave][l15][quad * 8]);
#pragma unroll
        for (int t = 0; t < 4; t++) {
            short8 vb = *(const short8*)(&Vt[t * 16 + l15][quad * 8]);
            O[t] = __builtin_amdgcn_mfma_f32_16x16x32_bf16(pa, vb, O[t], 0, 0, 0);
        }
    }
#pragma unroll
    for (int t = 0; t < 4; t++) {
#pragma unroll
        for (int r = 0; r < 4; r++) {
            int q = q0 + quad * 4 + r;
            out[q * D + h * HD + t * 16 + l15] = f2bf(O[t][r] / l[r]);
        }
    }
}

// ---------------------------------------------------------------------------
// Row LayerNorm: one wave per row of 512 f32, output f32. Grid NQ/4 = 512.
// ---------------------------------------------------------------------------
__global__ __launch_bounds__(256) void layernorm_kernel(
    const float* __restrict__ X, const float* __restrict__ g,
    const float* __restrict__ b, float* __restrict__ out)
{
    int wave = threadIdx.x >> 6, lane = threadIdx.x & 63;
    int row = blockIdx.x * 4 + wave;
    const float* xp = X + row * D;
    float v[8];
    float s = 0.f;
#pragma unroll
    for (int i = 0; i < 8; i++) { v[i] = xp[lane + i * 64]; s += v[i]; }
#pragma unroll
    for (int off = 1; off < 64; off <<= 1) s += __shfl_xor(s, off);
    float mu = s * (1.f / D);
    float var = 0.f;
#pragma unroll
    for (int i = 0; i < 8; i++) { float d = v[i] - mu; var += d * d; }
#pragma unroll
    for (int off = 1; off < 64; off <<= 1) var += __shfl_xor(var, off);
    float rstd = rsqrtf(var * (1.f / D) + 1e-5f);
#pragma unroll
    for (int i = 0; i < 8; i++) {
        int c = lane + i * 64;
        out[row * D + c] = (v[i] - mu) * rstd * g[c] + b[c];
    }
}

extern "C" void kernel_launch(void* const* d_in, const int* in_sizes, int n_in,
                              void* d_out, int out_size, void* d_ws, size_t ws_size,
                              hipStream_t stream) {
    const float* query_repr     = (const float*)d_in[0];
    const float* context_repr   = (const float*)d_in[1];
    const float* query_coords   = (const float*)d_in[2];
    const float* context_coords = (const float*)d_in[3];
    const float* Wq = (const float*)d_in[4];
    const float* bq = (const float*)d_in[5];
    const float* Wk = (const float*)d_in[6];
    const float* bk = (const float*)d_in[7];
    const float* Wv = (const float*)d_in[8];
    const float* bv = (const float*)d_in[9];
    const float* Wo = (const float*)d_in[10];
    const float* bo = (const float*)d_in[11];
    const float* ln_g = (const float*)d_in[12];
    const float* ln_b = (const float*)d_in[13];
    const float* log_scale = (const float*)d_in[14];
    const float* bph = (const float*)d_in[15];

    short* ws = (short*)d_ws;
    short* Xq_bf = ws;                       // 1,048,576 shorts (fallback only)
    short* Xc_bf = Xq_bf + NQ * D;           // 2,097,152 (fallback only)
    short* Wq_bf = Xc_bf + NC * D;           //   262,144 x4 (contiguous W region)
    short* Wk_bf = Wq_bf + D * D;
    short* Wv_bf = Wk_bf + D * D;
    short* Wo_bf = Wv_bf + D * D;
    short* Qw  = Wo_bf + D * D;              // 1,048,576
    short* Kw  = Qw + NQ * D;                // 2,097,152
    short* Vw  = Kw + NC * D;                // 2,097,152 (Vp [D][NC] permuted)
    short* Att = Vw + NC * D;                // 1,048,576
    float* Xf  = (float*)(Att + NQ * D);     // 1,048,576 f32
    short* Opart = (short*)(Xf + NQ * D);    // SPLIT*H*NQ*HD bf16 = 16.8 MB
    float* Lpart = (float*)(Opart + (size_t)SPLIT * H * NQ * HD);  // 0.5 MB
    size_t ws_needed_split = ((char*)(Lpart + (size_t)SPLIT * H * NQ)) - (char*)d_ws;

    if (ws_size >= ws_needed_split) {
        // 1. cast weights only (X-cast fused into QKV staging)
        cast_w<<<dim3(1024), 256, 0, stream>>>(Wq, Wk, Wv, Wo, Wq_bf);
        // 2. TILED Q+K+V projection with fused f32 X-cast (640 blocks)
        gemm_qkv_tiled_f32<<<dim3(640), 256, 0, stream>>>(
            query_repr, context_repr, Wq_bf, Wk_bf, Wv_bf, bq, bk, bv,
            Qw, Kw, Vw);
        // 3. attention (v10: XCD-swizzled grid) + combine
        attn_mfma_split10<<<dim3(1024), 256, 0, stream>>>(
            Qw, Kw, Vw, query_coords, context_coords, log_scale, bph,
            Opart, Lpart);
        attn_combine<<<dim3(H * NQ * HD / 256), 256, 0, stream>>>(
            Opart, Lpart, Att);
        // 4. TILED output projection + residual -> Xf (f32)
        gemm_out_tiled<<<dim3(128), 256, 0, stream>>>(
            Att, Wo_bf, bo, query_repr, Xf);
        // 5. LayerNorm -> f32 output
        layernorm_kernel<<<dim3(NQ / 4), 256, 0, stream>>>(
            Xf, ln_g, ln_b, (float*)d_out);
    } else {
        cast_all<<<dim3(4096), 256, 0, stream>>>(
            query_repr, context_repr, Wq, Wk, Wv, Wo, Xq_bf);
        gemm_bt_bias<<<dim3((NQ / 16) * 8 / 4), 256, 0, stream>>>(
            Xq_bf, Wq_bf, bq, Qw, NQ);
        gemm_bt_bias<<<dim3((NC / 16) * 8 / 4), 256, 0, stream>>>(
            Xc_bf, Wk_bf, bk, Kw, NC);
        gemm_bt_bias<<<dim3((NC / 16) * 8 / 4), 256, 0, stream>>>(
            Xc_bf, Wv_bf, bv, Vw, NC);
        attn_mfma<<<dim3(NQ / 64, H), 256, 0, stream>>>(
            Qw, Kw, Vw, query_coords, context_coords, log_scale, bph, Att);
        gemm_bt_bias_res_f32<<<dim3((NQ / 16) * 8 / 4), 256, 0, stream>>>(
            Att, Wo_bf, bo, query_repr, Xf, NQ);
        layernorm_kernel<<<dim3(NQ / 4), 256, 0, stream>>>(
            Xf, ln_g, ln_b, (float*)d_out);
    }
}

// Round 14
// 166.944 us; speedup vs baseline: 1.0427x; 1.0427x over previous
//
#include <hip/hip_runtime.h>

#define D 512
#define H 8
#define HD 64
#define NQ 2048
#define NC 4096
#define SPLIT 8
#define CLEN (NC / SPLIT)   // 512 contexts per split chunk
#define NT (CLEN / 32)      // 16 tiles per chunk
#define M0 3.0f             // fixed softmax max: scores provably < 3
#define KP2 136             // K LDS row stride (shorts): 272B, 16B-aligned
#define VP 40               // V LDS row stride (shorts): 80B, 16B-aligned

// tiled-GEMM geometry
#define TBM 128
#define TBN 64
#define TBK 32
#define TPAD 40             // LDS row stride in shorts: 80B, 16B-aligned

typedef __attribute__((ext_vector_type(8))) short short8;
typedef __attribute__((ext_vector_type(4))) short short4v;
typedef __attribute__((ext_vector_type(4))) float float4v;
typedef __attribute__((ext_vector_type(4))) int int4v;

__device__ inline float bf2f(short s) {
    unsigned int u = ((unsigned int)(unsigned short)s) << 16;
    return __builtin_bit_cast(float, u);
}
__device__ inline short f2bf(float f) {
    unsigned int u = __builtin_bit_cast(unsigned int, f);
    u = (u + 0x7FFF + ((u >> 16) & 1)) >> 16;   // round-to-nearest-even
    return (short)u;
}
// pack two f32 -> one dword of 2 bf16 (RNE), single HW instruction
__device__ inline int cvtpk(float a, float b) {
    int w;
    asm("v_cvt_pk_bf16_f32 %0, %1, %2" : "=v"(w) : "v"(a), "v"(b));
    return w;
}

// ---------------------------------------------------------------------------
// Cast f32 -> bf16 for the 6 MFMA-operand tensors. Grid 4096 x 256.
// ---------------------------------------------------------------------------
__global__ __launch_bounds__(256) void cast_all(
    const float* __restrict__ s0, const float* __restrict__ s1,
    const float* __restrict__ s2, const float* __restrict__ s3,
    const float* __restrict__ s4, const float* __restrict__ s5,
    short* __restrict__ dst)
{
    int i = blockIdx.x * 256 + threadIdx.x;
    const float* src; int off;
    if      (i < 262144) { src = s0; off = i; }
    else if (i < 786432) { src = s1; off = i - 262144; }
    else if (i < 851968) { src = s2; off = i - 786432; }
    else if (i < 917504) { src = s3; off = i - 851968; }
    else if (i < 983040) { src = s4; off = i - 917504; }
    else                 { src = s5; off = i - 983040; }
    float4v v = ((const float4v*)src)[off];
    short4v o;
    o.x = f2bf(v.x); o.y = f2bf(v.y); o.z = f2bf(v.z); o.w = f2bf(v.w);
    ((short4v*)dst)[i] = o;
}

// ---------------------------------------------------------------------------
// GEMM: out[M x D] = X @ W^T + bias. Wave computes 16x64 (fallback path).
// ---------------------------------------------------------------------------
__global__ __launch_bounds__(256) void gemm_bt_bias(
    const short* __restrict__ X, const short* __restrict__ W,
    const float* __restrict__ bias, short* __restrict__ out, int M)
{
    int wave = threadIdx.x >> 6, lane = threadIdx.x & 63;
    int gt = blockIdx.x * 4 + wave;
    int tm = gt >> 3;
    int tg = gt & 7;
    if (tm >= (M >> 4)) return;
    int l15 = lane & 15, quad = lane >> 4;
    const short* xp = X + (tm * 16 + l15) * D + quad * 8;
    const short* wp = W + (tg * 64 + l15) * D + quad * 8;
    float4v a0 = {0,0,0,0}, a1 = {0,0,0,0}, a2 = {0,0,0,0}, a3 = {0,0,0,0};
#pragma unroll
    for (int k = 0; k < D; k += 32) {
        short8 a  = *(const short8*)(xp + k);
        short8 b0 = *(const short8*)(wp + k);
        short8 b1 = *(const short8*)(wp + 16 * D + k);
        short8 b2 = *(const short8*)(wp + 32 * D + k);
        short8 b3 = *(const short8*)(wp + 48 * D + k);
        a0 = __builtin_amdgcn_mfma_f32_16x16x32_bf16(a, b0, a0, 0, 0, 0);
        a1 = __builtin_amdgcn_mfma_f32_16x16x32_bf16(a, b1, a1, 0, 0, 0);
        a2 = __builtin_amdgcn_mfma_f32_16x16x32_bf16(a, b2, a2, 0, 0, 0);
        a3 = __builtin_amdgcn_mfma_f32_16x16x32_bf16(a, b3, a3, 0, 0, 0);
    }
    int orow = tm * 16 + quad * 4;
    float4v accs[4] = {a0, a1, a2, a3};
#pragma unroll
    for (int j = 0; j < 4; j++) {
        int col = tg * 64 + j * 16 + l15;
        float bv = bias[col];
#pragma unroll
        for (int r = 0; r < 4; r++)
            out[(orow + r) * D + col] = f2bf(accs[j][r] + bv);
    }
}

// ---------------------------------------------------------------------------
// TILED Q+K+V projection GEMM (round-10/11 PASSED bf16 body) + XCD-aware
// block remap: within each section, local d -> x=d&7, y=d>>3,
// m = x*(MT/8) + (y>>3), n = y&7 (bijective). All 8 n-blocks sharing an
// A-panel (128 rows, 128KB) satisfy global_blk%8 == x -> same XCD -> panel
// fetched once per L2 (round-12 proved blk%8 == XCD via attn FETCH drop).
// Grid 640: blk 0..127 Q (MT=16) | 128..383 K (MT=32) | 384..639 V (MT=32).
// ---------------------------------------------------------------------------
__global__ __launch_bounds__(256) void gemm_qkv_tiled(
    const short* __restrict__ Xq, const short* __restrict__ Xc,
    const short* __restrict__ Wq, const short* __restrict__ Wk,
    const short* __restrict__ Wv,
    const float* __restrict__ bq, const float* __restrict__ bk,
    const float* __restrict__ bv,
    short* __restrict__ Qout, short* __restrict__ Kout,
    short* __restrict__ VoutT)
{
    __shared__ __align__(16) short Ab[2][TBM * TPAD];   // 20480 B
    __shared__ __align__(16) short Bb[2][TBN * TPAD];   // 10240 B

    int tid = threadIdx.x;
    int wave = tid >> 6, lane = tid & 63;
    int quad = lane >> 4, l15 = lane & 15;

    int blk = blockIdx.x;
    const short *X, *W;
    const float* bias;
    short* outp;
    int bm, bn, vmode;
    {
        int local, mtdiv8;
        if (blk < 128)      { local = blk;       mtdiv8 = 2; }   // Q: MT=16
        else if (blk < 384) { local = blk - 128; mtdiv8 = 4; }   // K: MT=32
        else                { local = blk - 384; mtdiv8 = 4; }   // V: MT=32
        int x = local & 7, y = local >> 3;
        int m = x * mtdiv8 + (y >> 3);
        int n = y & 7;
        bm = m * TBM; bn = n * TBN;
    }
    if (blk < 128)      { X = Xq; W = Wq; bias = bq; outp = Qout;  vmode = 0; }
    else if (blk < 384) { X = Xc; W = Wk; bias = bk; outp = Kout;  vmode = 0; }
    else                { X = Xc; W = Wv; bias = bv; outp = VoutT; vmode = 1; }

    // staging maps: A 128x32 (2 short8/thread), B 64x32 (1 short8/thread)
    int ar = tid >> 1, ac = (tid & 1) * 16;
    int br = tid >> 2, bc = (tid & 3) * 8;
    const short* ag = X + (size_t)(bm + ar) * D + ac;
    const short* bg = W + (size_t)(bn + br) * D + bc;
    short* aw0 = &Ab[0][ar * TPAD + ac];
    short* aw1 = &Ab[1][ar * TPAD + ac];
    short* bw0 = &Bb[0][br * TPAD + bc];
    short* bw1 = &Bb[1][br * TPAD + bc];

    short8 ra0, ra1, rb;

#define GLOAD(ks) { const short* ap_ = ag + (ks) * TBK;                        \
        ra0 = *(const short8*)(ap_);                                           \
        ra1 = *(const short8*)(ap_ + 8);                                       \
        rb  = *(const short8*)(bg + (ks) * TBK); }
#define GDSW0 { *(short8*)aw0 = ra0; *(short8*)(aw0 + 8) = ra1;                \
                *(short8*)bw0 = rb; }
#define GDSW1 { *(short8*)aw1 = ra0; *(short8*)(aw1 + 8) = ra1;                \
                *(short8*)bw1 = rb; }

    float4v c00 = {0,0,0,0}, c01 = {0,0,0,0}, c02 = {0,0,0,0}, c03 = {0,0,0,0};
    float4v c10 = {0,0,0,0}, c11 = {0,0,0,0}, c12 = {0,0,0,0}, c13 = {0,0,0,0};

#define GCOMP(B)                                                               \
    {                                                                          \
        const short* abase = &Ab[B][(wave * 32 + l15) * TPAD + quad * 8];      \
        const short* bbase = &Bb[B][l15 * TPAD + quad * 8];                    \
        short8 a0 = *(const short8*)(abase);                                   \
        short8 a1 = *(const short8*)(abase + 16 * TPAD);                       \
        short8 b0 = *(const short8*)(bbase);                                   \
        short8 b1 = *(const short8*)(bbase + 16 * TPAD);                       \
        short8 b2 = *(const short8*)(bbase + 32 * TPAD);                       \
        short8 b3 = *(const short8*)(bbase + 48 * TPAD);                       \
        c00 = __builtin_amdgcn_mfma_f32_16x16x32_bf16(a0, b0, c00, 0, 0, 0);   \
        c01 = __builtin_amdgcn_mfma_f32_16x16x32_bf16(a0, b1, c01, 0, 0, 0);   \
        c02 = __builtin_amdgcn_mfma_f32_16x16x32_bf16(a0, b2, c02, 0, 0, 0);   \
        c03 = __builtin_amdgcn_mfma_f32_16x16x32_bf16(a0, b3, c03, 0, 0, 0);   \
        c10 = __builtin_amdgcn_mfma_f32_16x16x32_bf16(a1, b0, c10, 0, 0, 0);   \
        c11 = __builtin_amdgcn_mfma_f32_16x16x32_bf16(a1, b1, c11, 0, 0, 0);   \
        c12 = __builtin_amdgcn_mfma_f32_16x16x32_bf16(a1, b2, c12, 0, 0, 0);   \
        c13 = __builtin_amdgcn_mfma_f32_16x16x32_bf16(a1, b3, c13, 0, 0, 0);   \
    }

    GLOAD(0);
    GDSW0;
    GLOAD(1);
    __syncthreads();

    for (int t = 0; t < 14; t += 2) {
        GDSW1;
        GLOAD(t + 2);
        GCOMP(0);
        __syncthreads();
        GDSW0;
        GLOAD(t + 3);
        GCOMP(1);
        __syncthreads();
    }
    GDSW1;
    GCOMP(0);
    __syncthreads();
    GCOMP(1);

#undef GLOAD
#undef GDSW0
#undef GDSW1
#undef GCOMP

    float4v accs[2][4] = {{c00, c01, c02, c03}, {c10, c11, c12, c13}};
    if (vmode == 0) {
#pragma unroll
        for (int mf = 0; mf < 2; mf++) {
            int orow = bm + wave * 32 + mf * 16 + quad * 4;
#pragma unroll
            for (int nf = 0; nf < 4; nf++) {
                int col = bn + nf * 16 + l15;
                float bb_ = bias[col];
#pragma unroll
                for (int r = 0; r < 4; r++)
                    outp[(size_t)(orow + r) * D + col] = f2bf(accs[mf][nf][r] + bb_);
            }
        }
    } else {
#pragma unroll
        for (int mf = 0; mf < 2; mf++) {
            int orow = bm + wave * 32 + mf * 16 + quad * 4;
            int a = (orow & 31) >> 2;
            int posb = (a < 4) ? (8 * a) : (8 * (a - 4) + 4);
            int cp = (orow & ~31) + posb;
#pragma unroll
            for (int nf = 0; nf < 4; nf++) {
                int col = bn + nf * 16 + l15;
                float bb_ = bias[col];
                short4v o;
#pragma unroll
                for (int r = 0; r < 4; r++) o[r] = f2bf(accs[mf][nf][r] + bb_);
                *(short4v*)(outp + (size_t)col * NC + cp) = o;
            }
        }
    }
}

// ---------------------------------------------------------------------------
// TILED output projection: Xf = Att @ Wo^T + bo + resid (f32 out).
// Round-11 PASSED body + XCD-aware block remap (MT=16). Grid 128.
// ---------------------------------------------------------------------------
__global__ __launch_bounds__(256) void gemm_out_tiled(
    const short* __restrict__ X, const short* __restrict__ W,
    const float* __restrict__ bias, const float* __restrict__ resid,
    float* __restrict__ out)
{
    __shared__ __align__(16) short Ab[2][TBM * TPAD];   // 20480 B
    __shared__ __align__(16) short Bb[2][TBN * TPAD];   // 10240 B

    int tid = threadIdx.x;
    int wave = tid >> 6, lane = tid & 63;
    int quad = lane >> 4, l15 = lane & 15;

    int blk = blockIdx.x;
    int x = blk & 7, y = blk >> 3;          // y in [0,16)
    int bm = (x * 2 + (y >> 3)) * TBM;      // MT=16
    int bn = (y & 7) * TBN;

    int ar = tid >> 1, ac = (tid & 1) * 16;
    int br = tid >> 2, bc = (tid & 3) * 8;
    const short* ag = X + (size_t)(bm + ar) * D + ac;
    const short* bg = W + (size_t)(bn + br) * D + bc;
    short* aw0 = &Ab[0][ar * TPAD + ac];
    short* aw1 = &Ab[1][ar * TPAD + ac];
    short* bw0 = &Bb[0][br * TPAD + bc];
    short* bw1 = &Bb[1][br * TPAD + bc];

    short8 ra0, ra1, rb;

#define GLOAD(ks) { const short* ap_ = ag + (ks) * TBK;                        \
        ra0 = *(const short8*)(ap_);                                           \
        ra1 = *(const short8*)(ap_ + 8);                                       \
        rb  = *(const short8*)(bg + (ks) * TBK); }
#define GDSW0 { *(short8*)aw0 = ra0; *(short8*)(aw0 + 8) = ra1;                \
                *(short8*)bw0 = rb; }
#define GDSW1 { *(short8*)aw1 = ra0; *(short8*)(aw1 + 8) = ra1;                \
                *(short8*)bw1 = rb; }

    float4v c00 = {0,0,0,0}, c01 = {0,0,0,0}, c02 = {0,0,0,0}, c03 = {0,0,0,0};
    float4v c10 = {0,0,0,0}, c11 = {0,0,0,0}, c12 = {0,0,0,0}, c13 = {0,0,0,0};

#define GCOMP(B)                                                               \
    {                                                                          \
        const short* abase = &Ab[B][(wave * 32 + l15) * TPAD + quad * 8];      \
        const short* bbase = &Bb[B][l15 * TPAD + quad * 8];                    \
        short8 a0 = *(const short8*)(abase);                                   \
        short8 a1 = *(const short8*)(abase + 16 * TPAD);                       \
        short8 b0 = *(const short8*)(bbase);                                   \
        short8 b1 = *(const short8*)(bbase + 16 * TPAD);                       \
        short8 b2 = *(const short8*)(bbase + 32 * TPAD);                       \
        short8 b3 = *(const short8*)(bbase + 48 * TPAD);                       \
        c00 = __builtin_amdgcn_mfma_f32_16x16x32_bf16(a0, b0, c00, 0, 0, 0);   \
        c01 = __builtin_amdgcn_mfma_f32_16x16x32_bf16(a0, b1, c01, 0, 0, 0);   \
        c02 = __builtin_amdgcn_mfma_f32_16x16x32_bf16(a0, b2, c02, 0, 0, 0);   \
        c03 = __builtin_amdgcn_mfma_f32_16x16x32_bf16(a0, b3, c03, 0, 0, 0);   \
        c10 = __builtin_amdgcn_mfma_f32_16x16x32_bf16(a1, b0, c10, 0, 0, 0);   \
        c11 = __builtin_amdgcn_mfma_f32_16x16x32_bf16(a1, b1, c11, 0, 0, 0);   \
        c12 = __builtin_amdgcn_mfma_f32_16x16x32_bf16(a1, b2, c12, 0, 0, 0);   \
        c13 = __builtin_amdgcn_mfma_f32_16x16x32_bf16(a1, b3, c13, 0, 0, 0);   \
    }

    GLOAD(0);
    GDSW0;
    GLOAD(1);
    __syncthreads();

    for (int t = 0; t < 14; t += 2) {
        GDSW1;
        GLOAD(t + 2);
        GCOMP(0);
        __syncthreads();
        GDSW0;
        GLOAD(t + 3);
        GCOMP(1);
        __syncthreads();
    }
    GDSW1;
    GCOMP(0);
    __syncthreads();
    GCOMP(1);

#undef GLOAD
#undef GDSW0
#undef GDSW1
#undef GCOMP

    float4v accs[2][4] = {{c00, c01, c02, c03}, {c10, c11, c12, c13}};
#pragma unroll
    for (int mf = 0; mf < 2; mf++) {
        int orow = bm + wave * 32 + mf * 16 + quad * 4;
#pragma unroll
        for (int nf = 0; nf < 4; nf++) {
            int col = bn + nf * 16 + l15;
            float bb_ = bias[col];
#pragma unroll
            for (int r = 0; r < 4; r++)
                out[(size_t)(orow + r) * D + col] =
                    accs[mf][nf][r] + bb_ + resid[(size_t)(orow + r) * D + col];
        }
    }
}

// Fallback: naive res GEMM writing f32 (used with separate layernorm_kernel).
__global__ __launch_bounds__(256) void gemm_bt_bias_res_f32(
    const short* __restrict__ X, const short* __restrict__ W,
    const float* __restrict__ bias, const float* __restrict__ resid,
    float* __restrict__ out, int M)
{
    int wave = threadIdx.x >> 6, lane = threadIdx.x & 63;
    int gt = blockIdx.x * 4 + wave;
    int tm = gt >> 3;
    int tg = gt & 7;
    if (tm >= (M >> 4)) return;
    int l15 = lane & 15, quad = lane >> 4;
    const short* xp = X + (tm * 16 + l15) * D + quad * 8;
    const short* wp = W + (tg * 64 + l15) * D + quad * 8;
    float4v a0 = {0,0,0,0}, a1 = {0,0,0,0}, a2 = {0,0,0,0}, a3 = {0,0,0,0};
#pragma unroll
    for (int k = 0; k < D; k += 32) {
        short8 a  = *(const short8*)(xp + k);
        short8 b0 = *(const short8*)(wp + k);
        short8 b1 = *(const short8*)(wp + 16 * D + k);
        short8 b2 = *(const short8*)(wp + 32 * D + k);
        short8 b3 = *(const short8*)(wp + 48 * D + k);
        a0 = __builtin_amdgcn_mfma_f32_16x16x32_bf16(a, b0, a0, 0, 0, 0);
        a1 = __builtin_amdgcn_mfma_f32_16x16x32_bf16(a, b1, a1, 0, 0, 0);
        a2 = __builtin_amdgcn_mfma_f32_16x16x32_bf16(a, b2, a2, 0, 0, 0);
        a3 = __builtin_amdgcn_mfma_f32_16x16x32_bf16(a, b3, a3, 0, 0, 0);
    }
    int orow = tm * 16 + quad * 4;
    float4v accs[4] = {a0, a1, a2, a3};
#pragma unroll
    for (int j = 0; j < 4; j++) {
        int col = tg * 64 + j * 16 + l15;
        float bv = bias[col];
#pragma unroll
        for (int r = 0; r < 4; r++) {
            int q = orow + r;
            out[q * D + col] = accs[j][r] + bv + resid[q * D + col];
        }
    }
}

// ---------------------------------------------------------------------------
// MFMA flash attention v10 (round-12 PASSED): v9 body + XCD 1D-grid swizzle
// (FETCH 35 -> 12.4 MB verified). UNCHANGED.
// NOTE: cc-from-global (v7/v8) produced NaN twice — do not reintroduce.
// ---------------------------------------------------------------------------
__global__ __launch_bounds__(256) void attn_mfma_split10(
    const short* __restrict__ Q, const short* __restrict__ K,
    const short* __restrict__ Vp,
    const float* __restrict__ qc, const float* __restrict__ cc,
    const float* __restrict__ log_scale, const float* __restrict__ bph,
    short* __restrict__ Opart, float* __restrict__ Lpart)
{
    __shared__ __align__(16) short Klds[2][32 * KP2];   // 17408 B
    __shared__ __align__(16) short Vlds[2][128 * VP];   // 20480 B
    __shared__ __align__(16) float ccl[512];            //  2048 B (256 ctx)

    int tid = threadIdx.x;
    int wave = tid >> 6, lane = tid & 63;

    // XCD swizzle decode
    int d = blockIdx.x;
    int s = (d & 7) * 128 + (d >> 3);
    int bx = s & 31;
    int by = (s >> 5) & 3;
    int bz = s >> 7;

    int h0 = by * 2;                    // head pair (h0, h0+1)
    int sp = bz;
    int q0 = bx * 64 + wave * 16;
    int quad = lane >> 4, l15 = lane & 15;
    int cbase = sp * CLEN;

    const float LOG2E = 1.4426950408889634f;
    const float escale = 0.125f * LOG2E;
    const float M0L = M0 * LOG2E;
    float ebase = __expf(log_scale[0]);
    float bh0 = ebase * bph[h0] * LOG2E;
    float bh1 = ebase * bph[h0 + 1] * LOG2E;

    const short* qp = Q + (q0 + l15) * D + h0 * HD + quad * 8;
    short8 qa0_0 = *(const short8*)(qp);
    short8 qa1_0 = *(const short8*)(qp + 32);
    short8 qa0_1 = *(const short8*)(qp + 64);
    short8 qa1_1 = *(const short8*)(qp + 96);

    float qx = qc[(q0 + l15) * 2];
    float qy = qc[(q0 + l15) * 2 + 1];

    float lacc0 = 0.f, lacc1 = 0.f;
    float4v O00 = {0,0,0,0}, O01 = {0,0,0,0}, O02 = {0,0,0,0}, O03 = {0,0,0,0};
    float4v O10 = {0,0,0,0}, O11 = {0,0,0,0}, O12 = {0,0,0,0}, O13 = {0,0,0,0};

    int kr_ = tid >> 3, kc_ = tid & 7;
    int vr_ = tid >> 2, vc_ = tid & 3;
    const short* kg  = K + (size_t)h0 * HD + kc_ * 8;            // +(c0+kr_)*D
    const short* vg0 = Vp + (size_t)(h0 * HD + vr_) * NC + vc_ * 8;       // +c0
    const short* vg1 = Vp + (size_t)(h0 * HD + 64 + vr_) * NC + vc_ * 8;  // +c0
    short* kw0a = &Klds[0][kr_ * KP2 + kc_ * 8];
    short* kw1a = &Klds[1][kr_ * KP2 + kc_ * 8];
    short* vw0a = &Vlds[0][vr_ * VP + vc_ * 8];
    short* vw0b = &Vlds[0][(64 + vr_) * VP + vc_ * 8];
    short* vw1a = &Vlds[1][vr_ * VP + vc_ * 8];
    short* vw1b = &Vlds[1][(64 + vr_) * VP + vc_ * 8];

    short8 rka, rkb, rva, rvb;   // staged regs for the next tile

#define LOADR(c0_)                                                             \
    {                                                                          \
        const short* kp_ = kg + (size_t)((c0_) + kr_) * D;                     \
        rka = *(const short8*)(kp_);                                           \
        rkb = *(const short8*)(kp_ + 64);                                      \
        rva = *(const short8*)(vg0 + (c0_));                                   \
        rvb = *(const short8*)(vg1 + (c0_));                                   \
    }

#define DSW0 { *(short8*)kw0a = rka; *(short8*)(kw0a + 64) = rkb;              \
               *(short8*)vw0a = rva; *(short8*)vw0b = rvb; }
#define DSW1 { *(short8*)kw1a = rka; *(short8*)(kw1a + 64) = rkb;              \
               *(short8*)vw1a = rva; *(short8*)vw1b = rvb; }

    const float2* ccp = (const float2*)ccl;

#define HEAD(hoff, QA0, QA1, BH, LACC, OA, OB, OC, OD)                         \
    {                                                                          \
        short8 k00 = *(const short8*)(kb + l15 * KP2 + (hoff) + quad * 8);     \
        short8 k01 = *(const short8*)(kb + l15 * KP2 + (hoff) + 32 + quad * 8);\
        short8 k10 = *(const short8*)(kb + (16 + l15) * KP2 + (hoff) + quad * 8);\
        short8 k11 = *(const short8*)(kb + (16 + l15) * KP2 + (hoff) + 32 + quad * 8);\
        float4v s0 = {0,0,0,0}, s1 = {0,0,0,0};                                \
        s0 = __builtin_amdgcn_mfma_f32_16x16x32_bf16(k00, QA0, s0, 0, 0, 0);   \
        s0 = __builtin_amdgcn_mfma_f32_16x16x32_bf16(k01, QA1, s0, 0, 0, 0);   \
        s1 = __builtin_amdgcn_mfma_f32_16x16x32_bf16(k10, QA0, s1, 0, 0, 0);   \
        s1 = __builtin_amdgcn_mfma_f32_16x16x32_bf16(k11, QA1, s1, 0, 0, 0);   \
        short8 v0 = *(const short8*)(vb + ((hoff) / 64 * 64 + l15) * VP + quad * 8);       \
        short8 v1 = *(const short8*)(vb + ((hoff) / 64 * 64 + 16 + l15) * VP + quad * 8);  \
        short8 v2 = *(const short8*)(vb + ((hoff) / 64 * 64 + 32 + l15) * VP + quad * 8);  \
        short8 v3 = *(const short8*)(vb + ((hoff) / 64 * 64 + 48 + l15) * VP + quad * 8);  \
        float p00 = exp2f(__fmaf_rn(s0[0], escale, __fmaf_rn(-(BH), dA0, -M0L)));\
        float p01 = exp2f(__fmaf_rn(s0[1], escale, __fmaf_rn(-(BH), dA1, -M0L)));\
        float p02 = exp2f(__fmaf_rn(s0[2], escale, __fmaf_rn(-(BH), dA2, -M0L)));\
        float p03 = exp2f(__fmaf_rn(s0[3], escale, __fmaf_rn(-(BH), dA3, -M0L)));\
        float p10 = exp2f(__fmaf_rn(s1[0], escale, __fmaf_rn(-(BH), dB0, -M0L)));\
        float p11 = exp2f(__fmaf_rn(s1[1], escale, __fmaf_rn(-(BH), dB1, -M0L)));\
        float p12 = exp2f(__fmaf_rn(s1[2], escale, __fmaf_rn(-(BH), dB2, -M0L)));\
        float p13 = exp2f(__fmaf_rn(s1[3], escale, __fmaf_rn(-(BH), dB3, -M0L)));\
        LACC += ((p00 + p01) + (p02 + p03)) + ((p10 + p11) + (p12 + p13));     \
        int4v pw;                                                              \
        pw.x = cvtpk(p00, p01); pw.y = cvtpk(p02, p03);                        \
        pw.z = cvtpk(p10, p11); pw.w = cvtpk(p12, p13);                        \
        short8 pa = __builtin_bit_cast(short8, pw);                            \
        OA = __builtin_amdgcn_mfma_f32_16x16x32_bf16(pa, v0, OA, 0, 0, 0);     \
        OB = __builtin_amdgcn_mfma_f32_16x16x32_bf16(pa, v1, OB, 0, 0, 0);     \
        OC = __builtin_amdgcn_mfma_f32_16x16x32_bf16(pa, v2, OC, 0, 0, 0);     \
        OD = __builtin_amdgcn_mfma_f32_16x16x32_bf16(pa, v3, OD, 0, 0, 0);     \
    }

#define COMPUTE_TILE(B, lo)                                                    \
    {                                                                          \
        const short* kb = &Klds[B][0];                                         \
        const short* vb = &Vlds[B][0];                                         \
        float2 ca0 = ccp[(lo) + 4 * quad + 0], cb0 = ccp[(lo) + 16 + 4 * quad + 0];\
        float2 ca1 = ccp[(lo) + 4 * quad + 1], cb1 = ccp[(lo) + 16 + 4 * quad + 1];\
        float2 ca2 = ccp[(lo) + 4 * quad + 2], cb2 = ccp[(lo) + 16 + 4 * quad + 2];\
        float2 ca3 = ccp[(lo) + 4 * quad + 3], cb3 = ccp[(lo) + 16 + 4 * quad + 3];\
        float dx, dy;                                                          \
        dx = qx - ca0.x; dy = qy - ca0.y;                                      \
        float dA0 = __builtin_amdgcn_sqrtf(__fmaf_rn(dx, dx, dy * dy));        \
        dx = qx - ca1.x; dy = qy - ca1.y;                                      \
        float dA1 = __builtin_amdgcn_sqrtf(__fmaf_rn(dx, dx, dy * dy));        \
        dx = qx - ca2.x; dy = qy - ca2.y;                                      \
        float dA2 = __builtin_amdgcn_sqrtf(__fmaf_rn(dx, dx, dy * dy));        \
        dx = qx - ca3.x; dy = qy - ca3.y;                                      \
        float dA3 = __builtin_amdgcn_sqrtf(__fmaf_rn(dx, dx, dy * dy));        \
        dx = qx - cb0.x; dy = qy - cb0.y;                                      \
        float dB0 = __builtin_amdgcn_sqrtf(__fmaf_rn(dx, dx, dy * dy));        \
        dx = qx - cb1.x; dy = qy - cb1.y;                                      \
        float dB1 = __builtin_amdgcn_sqrtf(__fmaf_rn(dx, dx, dy * dy));        \
        dx = qx - cb2.x; dy = qy - cb2.y;                                      \
        float dB2 = __builtin_amdgcn_sqrtf(__fmaf_rn(dx, dx, dy * dy));        \
        dx = qx - cb3.x; dy = qy - cb3.y;                                      \
        float dB3 = __builtin_amdgcn_sqrtf(__fmaf_rn(dx, dx, dy * dy));        \
        HEAD(0,  qa0_0, qa1_0, bh0, lacc0, O00, O01, O02, O03)                 \
        HEAD(64, qa0_1, qa1_1, bh1, lacc1, O10, O11, O12, O13)                 \
    }

    // ---- prologue: cc phase A (256 ctx) -> LDS, tile0 -> buf0, tile1 -> regs
    ((float2*)ccl)[tid] = ((const float2*)cc)[cbase + tid];
    LOADR(cbase);
    DSW0;
    LOADR(cbase + 32);
    __syncthreads();

    // ---- main loop: 16 tiles, 2x-unrolled (static buffer indices) ----
    for (int t = 0; t < NT - 2; t += 2) {
        int c0 = cbase + t * 32;
        if (t == 8) {
            ((float2*)ccl)[tid] = ((const float2*)cc)[cbase + 256 + tid];
            __syncthreads();
        }
        DSW1;
        LOADR(c0 + 64);
        COMPUTE_TILE(0, (t & 7) * 32);
        __syncthreads();
        DSW0;
        LOADR(c0 + 96);
        COMPUTE_TILE(1, (t & 7) * 32 + 32);
        __syncthreads();
    }
    DSW1;
    COMPUTE_TILE(0, 192);   // tile 14, rel (14-8)*32
    __syncthreads();
    COMPUTE_TILE(1, 224);   // tile 15, rel (15-8)*32

#undef LOADR
#undef DSW0
#undef DSW1
#undef HEAD
#undef COMPUTE_TILE

    lacc0 += __shfl_xor(lacc0, 16);
    lacc0 += __shfl_xor(lacc0, 32);
    lacc1 += __shfl_xor(lacc1, 16);
    lacc1 += __shfl_xor(lacc1, 32);

    long base0 = (long)(sp * H + h0) * NQ;
    long base1 = base0 + NQ;
    float4v Oarr0[4] = {O00, O01, O02, O03};
    float4v Oarr1[4] = {O10, O11, O12, O13};
#pragma unroll
    for (int t = 0; t < 4; t++) {
#pragma unroll
        for (int r = 0; r < 4; r++) {
            int q = q0 + quad * 4 + r;
            Opart[(base0 + q) * HD + t * 16 + l15] = f2bf(Oarr0[t][r]);
            Opart[(base1 + q) * HD + t * 16 + l15] = f2bf(Oarr1[t][r]);
        }
    }
    if (lane < 16) {
        Lpart[base0 + q0 + lane] = lacc0;
        Lpart[base1 + q0 + lane] = lacc1;
    }
}

// Plain-sum combine (all splits share fixed max M0) -> bf16 Att.
__global__ __launch_bounds__(256) void attn_combine(
    const short* __restrict__ Opart, const float* __restrict__ Lpart,
    short* __restrict__ Att)
{
    int id = blockIdx.x * 256 + threadIdx.x;   // over H*NQ*HD = 2^20
    int d = id & 63;
    int q = (id >> 6) & (NQ - 1);
    int h = id >> 17;
    float L = 0.f, acc = 0.f;
#pragma unroll
    for (int s = 0; s < SPLIT; s++) {
        long b = (long)(s * H + h) * NQ + q;
        L   += Lpart[b];
        acc += bf2f(Opart[b * HD + d]);
    }
    Att[q * D + h * HD + d] = f2bf(acc / L);
}

// ---------------------------------------------------------------------------
// Fallback single-pass attention (exact online softmax) if ws is too small.
// Expects V row-major [NC][D], unscaled Q.
// ---------------------------------------------------------------------------
__global__ __launch_bounds__(256) void attn_mfma(
    const short* __restrict__ Q, const short* __restrict__ K,
    const short* __restrict__ V,
    const float* __restrict__ qc, const float* __restrict__ cc,
    const float* __restrict__ log_scale, const float* __restrict__ bph,
    short* __restrict__ out)
{
    __shared__ short Vt[HD][48];
    __shared__ short P[4][16][48];
    int wave = threadIdx.x >> 6, lane = threadIdx.x & 63;
    int h = blockIdx.y;
    int q0 = blockIdx.x * 64 + wave * 16;
    int quad = lane >> 4, l15 = lane & 15;
    const float scale = 0.125f;
    float bh = __expf(log_scale[0]) * bph[h];
    const short* qp = Q + (q0 + l15) * D + h * HD + quad * 8;
    short8 qa0 = *(const short8*)(qp);
    short8 qa1 = *(const short8*)(qp + 32);
    float qx[4], qy[4];
#pragma unroll
    for (int r = 0; r < 4; r++) {
        int q = q0 + quad * 4 + r;
        qx[r] = qc[q * 2]; qy[r] = qc[q * 2 + 1];
    }
    float m[4], l[4];
    float4v O[4];
#pragma unroll
    for (int r = 0; r < 4; r++) { m[r] = -1e30f; l[r] = 0.f; }
#pragma unroll
    for (int t = 0; t < 4; t++) O[t] = (float4v){0.f, 0.f, 0.f, 0.f};
    for (int c0 = 0; c0 < NC; c0 += 32) {
        __syncthreads();
        {
            int c = threadIdx.x >> 3;
            int dblk = (threadIdx.x & 7) * 8;
            short8 vv = *(const short8*)(V + (c0 + c) * D + h * HD + dblk);
#pragma unroll
            for (int j = 0; j < 8; j++) Vt[dblk + j][c] = vv[j];
        }
        const short* kp0 = K + (c0 + l15) * D + h * HD + quad * 8;
        const short* kp1 = kp0 + 16 * D;
        short8 kb00 = *(const short8*)(kp0);
        short8 kb01 = *(const short8*)(kp0 + 32);
        short8 kb10 = *(const short8*)(kp1);
        short8 kb11 = *(const short8*)(kp1 + 32);
        float4v s0 = {0,0,0,0}, s1 = {0,0,0,0};
        s0 = __builtin_amdgcn_mfma_f32_16x16x32_bf16(qa0, kb00, s0, 0, 0, 0);
        s0 = __builtin_amdgcn_mfma_f32_16x16x32_bf16(qa1, kb01, s0, 0, 0, 0);
        s1 = __builtin_amdgcn_mfma_f32_16x16x32_bf16(qa0, kb10, s1, 0, 0, 0);
        s1 = __builtin_amdgcn_mfma_f32_16x16x32_bf16(qa1, kb11, s1, 0, 0, 0);
        int cA = c0 + l15, cB = cA + 16;
        float cxA = cc[cA * 2], cyA = cc[cA * 2 + 1];
        float cxB = cc[cB * 2], cyB = cc[cB * 2 + 1];
#pragma unroll
        for (int r = 0; r < 4; r++) {
            float dxA = qx[r] - cxA, dyA = qy[r] - cyA;
            float dxB = qx[r] - cxB, dyB = qy[r] - cyB;
            float v0 = s0[r] * scale - bh * sqrtf(dxA * dxA + dyA * dyA);
            float v1 = s1[r] * scale - bh * sqrtf(dxB * dxB + dyB * dyB);
            float mx = fmaxf(v0, v1);
#pragma unroll
            for (int off = 1; off < 16; off <<= 1) mx = fmaxf(mx, __shfl_xor(mx, off));
            float mnew = fmaxf(m[r], mx);
            float alpha = __expf(m[r] - mnew);
            float p0 = __expf(v0 - mnew);
            float p1 = __expf(v1 - mnew);
            float ps = p0 + p1;
#pragma unroll
            for (int off = 1; off < 16; off <<= 1) ps += __shfl_xor(ps, off);
            l[r] = l[r] * alpha + ps;
            m[r] = mnew;
#pragma unroll
            for (int t = 0; t < 4; t++) O[t][r] *= alpha;
            P[wave][quad * 4 + r][l15]      = f2bf(p0);
            P[wave][quad * 4 + r][16 + l15] = f2bf(p1);
        }
        __syncthreads();
        short8 pa = *(const short8*)(&P[wave][l15][quad * 8]);
#pragma unroll
        for (int t = 0; t < 4; t++) {
            short8 vb = *(const short8*)(&Vt[t * 16 + l15][quad * 8]);
            O[t] = __builtin_amdgcn_mfma_f32_16x16x32_bf16(pa, vb, O[t], 0, 0, 0);
        }
    }
#pragma unroll
    for (int t = 0; t < 4; t++) {
#pragma unroll
        for (int r = 0; r < 4; r++) {
            int q = q0 + quad * 4 + r;
            out[q * D + h * HD + t * 16 + l15] = f2bf(O[t][r] / l[r]);
        }
    }
}

// ---------------------------------------------------------------------------
// Row LayerNorm: one wave per row of 512 f32, output f32. Grid NQ/4 = 512.
// ---------------------------------------------------------------------------
__global__ __launch_bounds__(256) void layernorm_kernel(
    const float* __restrict__ X, const float* __restrict__ g,
    const float* __restrict__ b, float* __restrict__ out)
{
    int wave = threadIdx.x >> 6, lane = threadIdx.x & 63;
    int row = blockIdx.x * 4 + wave;
    const float* xp = X + row * D;
    float v[8];
    float s = 0.f;
#pragma unroll
    for (int i = 0; i < 8; i++) { v[i] = xp[lane + i * 64]; s += v[i]; }
#pragma unroll
    for (int off = 1; off < 64; off <<= 1) s += __shfl_xor(s, off);
    float mu = s * (1.f / D);
    float var = 0.f;
#pragma unroll
    for (int i = 0; i < 8; i++) { float d = v[i] - mu; var += d * d; }
#pragma unroll
    for (int off = 1; off < 64; off <<= 1) var += __shfl_xor(var, off);
    float rstd = rsqrtf(var * (1.f / D) + 1e-5f);
#pragma unroll
    for (int i = 0; i < 8; i++) {
        int c = lane + i * 64;
        out[row * D + c] = (v[i] - mu) * rstd * g[c] + b[c];
    }
}

extern "C" void kernel_launch(void* const* d_in, const int* in_sizes, int n_in,
                              void* d_out, int out_size, void* d_ws, size_t ws_size,
                              hipStream_t stream) {
    const float* query_repr     = (const float*)d_in[0];
    const float* context_repr   = (const float*)d_in[1];
    const float* query_coords   = (const float*)d_in[2];
    const float* context_coords = (const float*)d_in[3];
    const float* Wq = (const float*)d_in[4];
    const float* bq = (const float*)d_in[5];
    const float* Wk = (const float*)d_in[6];
    const float* bk = (const float*)d_in[7];
    const float* Wv = (const float*)d_in[8];
    const float* bv = (const float*)d_in[9];
    const float* Wo = (const float*)d_in[10];
    const float* bo = (const float*)d_in[11];
    const float* ln_g = (const float*)d_in[12];
    const float* ln_b = (const float*)d_in[13];
    const float* log_scale = (const float*)d_in[14];
    const float* bph = (const float*)d_in[15];

    short* ws = (short*)d_ws;
    short* Xq_bf = ws;                       // 1,048,576 shorts
    short* Xc_bf = Xq_bf + NQ * D;           // 2,097,152
    short* Wq_bf = Xc_bf + NC * D;           //   262,144 x4
    short* Wk_bf = Wq_bf + D * D;
    short* Wv_bf = Wk_bf + D * D;
    short* Wo_bf = Wv_bf + D * D;
    short* Qw  = Wo_bf + D * D;              // 1,048,576
    short* Kw  = Qw + NQ * D;                // 2,097,152
    short* Vw  = Kw + NC * D;                // 2,097,152 (Vp [D][NC] permuted)
    short* Att = Vw + NC * D;                // 1,048,576
    float* Xf  = (float*)(Att + NQ * D);     // 1,048,576 f32
    short* Opart = (short*)(Xf + NQ * D);    // SPLIT*H*NQ*HD bf16 = 16.8 MB
    float* Lpart = (float*)(Opart + (size_t)SPLIT * H * NQ * HD);  // 0.5 MB
    size_t ws_needed_split = ((char*)(Lpart + (size_t)SPLIT * H * NQ)) - (char*)d_ws;

    // 1. cast MFMA operands to bf16 (round-11 known-good path)
    cast_all<<<dim3(4096), 256, 0, stream>>>(
        query_repr, context_repr, Wq, Wk, Wv, Wo, Xq_bf);

    if (ws_size >= ws_needed_split) {
        // 2. TILED Q+K+V projection (bf16 body + XCD block remap), 640 blocks
        gemm_qkv_tiled<<<dim3(640), 256, 0, stream>>>(
            Xq_bf, Xc_bf, Wq_bf, Wk_bf, Wv_bf, bq, bk, bv, Qw, Kw, Vw);
        // 3. attention (v10: XCD-swizzled grid) + combine
        attn_mfma_split10<<<dim3(1024), 256, 0, stream>>>(
            Qw, Kw, Vw, query_coords, context_coords, log_scale, bph,
            Opart, Lpart);
        attn_combine<<<dim3(H * NQ * HD / 256), 256, 0, stream>>>(
            Opart, Lpart, Att);
        // 4. TILED output projection + residual (XCD remap) -> Xf (f32)
        gemm_out_tiled<<<dim3(128), 256, 0, stream>>>(
            Att, Wo_bf, bo, query_repr, Xf);
        // 5. LayerNorm -> f32 output
        layernorm_kernel<<<dim3(NQ / 4), 256, 0, stream>>>(
            Xf, ln_g, ln_b, (float*)d_out);
    } else {
        gemm_bt_bias<<<dim3((NQ / 16) * 8 / 4), 256, 0, stream>>>(
            Xq_bf, Wq_bf, bq, Qw, NQ);
        gemm_bt_bias<<<dim3((NC / 16) * 8 / 4), 256, 0, stream>>>(
            Xc_bf, Wk_bf, bk, Kw, NC);
        gemm_bt_bias<<<dim3((NC / 16) * 8 / 4), 256, 0, stream>>>(
            Xc_bf, Wv_bf, bv, Vw, NC);
        attn_mfma<<<dim3(NQ / 64, H), 256, 0, stream>>>(
            Qw, Kw, Vw, query_coords, context_coords, log_scale, bph, Att);
        gemm_bt_bias_res_f32<<<dim3((NQ / 16) * 8 / 4), 256, 0, stream>>>(
            Att, Wo_bf, bo, query_repr, Xf, NQ);
        layernorm_kernel<<<dim3(NQ / 4), 256, 0, stream>>>(
            Xf, ln_g, ln_b, (float*)d_out);
    }
}

// Round 15
// 164.525 us; speedup vs baseline: 1.0581x; 1.0147x over previous
//
#include <hip/hip_runtime.h>

#define D 512
#define H 8
#define HD 64
#define NQ 2048
#define NC 4096
#define SPLIT 8
#define CLEN (NC / SPLIT)   // 512 contexts per split chunk
#define NT (CLEN / 32)      // 16 tiles per chunk
#define M0 3.0f             // fixed softmax max: scores provably < 3
#define KP2 136             // K LDS row stride (shorts): 272B, 16B-aligned
#define VP 40               // V LDS row stride (shorts): 80B, 16B-aligned

// tiled-GEMM geometry (TBM=64 this round: grid x2 -> 5 blocks/CU on qkv)
#define TBM 64
#define TBN 64
#define TBK 32
#define TPAD 40             // LDS row stride in shorts: 80B, 16B-aligned

typedef __attribute__((ext_vector_type(8))) short short8;
typedef __attribute__((ext_vector_type(4))) short short4v;
typedef __attribute__((ext_vector_type(4))) float float4v;
typedef __attribute__((ext_vector_type(4))) int int4v;

__device__ inline float bf2f(short s) {
    unsigned int u = ((unsigned int)(unsigned short)s) << 16;
    return __builtin_bit_cast(float, u);
}
__device__ inline short f2bf(float f) {
    unsigned int u = __builtin_bit_cast(unsigned int, f);
    u = (u + 0x7FFF + ((u >> 16) & 1)) >> 16;   // round-to-nearest-even
    return (short)u;
}
// pack two f32 -> one dword of 2 bf16 (RNE), single HW instruction
__device__ inline int cvtpk(float a, float b) {
    int w;
    asm("v_cvt_pk_bf16_f32 %0, %1, %2" : "=v"(w) : "v"(a), "v"(b));
    return w;
}

// ---------------------------------------------------------------------------
// Cast f32 -> bf16 for the 6 MFMA-operand tensors. Grid 4096 x 256.
// ---------------------------------------------------------------------------
__global__ __launch_bounds__(256) void cast_all(
    const float* __restrict__ s0, const float* __restrict__ s1,
    const float* __restrict__ s2, const float* __restrict__ s3,
    const float* __restrict__ s4, const float* __restrict__ s5,
    short* __restrict__ dst)
{
    int i = blockIdx.x * 256 + threadIdx.x;
    const float* src; int off;
    if      (i < 262144) { src = s0; off = i; }
    else if (i < 786432) { src = s1; off = i - 262144; }
    else if (i < 851968) { src = s2; off = i - 786432; }
    else if (i < 917504) { src = s3; off = i - 851968; }
    else if (i < 983040) { src = s4; off = i - 917504; }
    else                 { src = s5; off = i - 983040; }
    float4v v = ((const float4v*)src)[off];
    short4v o;
    o.x = f2bf(v.x); o.y = f2bf(v.y); o.z = f2bf(v.z); o.w = f2bf(v.w);
    ((short4v*)dst)[i] = o;
}

// ---------------------------------------------------------------------------
// GEMM: out[M x D] = X @ W^T + bias. Wave computes 16x64 (fallback path).
// ---------------------------------------------------------------------------
__global__ __launch_bounds__(256) void gemm_bt_bias(
    const short* __restrict__ X, const short* __restrict__ W,
    const float* __restrict__ bias, short* __restrict__ out, int M)
{
    int wave = threadIdx.x >> 6, lane = threadIdx.x & 63;
    int gt = blockIdx.x * 4 + wave;
    int tm = gt >> 3;
    int tg = gt & 7;
    if (tm >= (M >> 4)) return;
    int l15 = lane & 15, quad = lane >> 4;
    const short* xp = X + (tm * 16 + l15) * D + quad * 8;
    const short* wp = W + (tg * 64 + l15) * D + quad * 8;
    float4v a0 = {0,0,0,0}, a1 = {0,0,0,0}, a2 = {0,0,0,0}, a3 = {0,0,0,0};
#pragma unroll
    for (int k = 0; k < D; k += 32) {
        short8 a  = *(const short8*)(xp + k);
        short8 b0 = *(const short8*)(wp + k);
        short8 b1 = *(const short8*)(wp + 16 * D + k);
        short8 b2 = *(const short8*)(wp + 32 * D + k);
        short8 b3 = *(const short8*)(wp + 48 * D + k);
        a0 = __builtin_amdgcn_mfma_f32_16x16x32_bf16(a, b0, a0, 0, 0, 0);
        a1 = __builtin_amdgcn_mfma_f32_16x16x32_bf16(a, b1, a1, 0, 0, 0);
        a2 = __builtin_amdgcn_mfma_f32_16x16x32_bf16(a, b2, a2, 0, 0, 0);
        a3 = __builtin_amdgcn_mfma_f32_16x16x32_bf16(a, b3, a3, 0, 0, 0);
    }
    int orow = tm * 16 + quad * 4;
    float4v accs[4] = {a0, a1, a2, a3};
#pragma unroll
    for (int j = 0; j < 4; j++) {
        int col = tg * 64 + j * 16 + l15;
        float bv = bias[col];
#pragma unroll
        for (int r = 0; r < 4; r++)
            out[(orow + r) * D + col] = f2bf(accs[j][r] + bv);
    }
}

// ---------------------------------------------------------------------------
// TILED Q+K+V projection GEMM, TBM=64 (occupancy fix: grid 1280 = 5/CU,
// LDS 20480 B; was 640 blocks = 2.5/CU -> barrier-latency-bound at 245 GF).
// Numerics bit-identical (same per-element MFMA k-chain). XCD remap kept:
// local -> x=d&7, y=d>>3; m = x*(MT/8)+(y>>3); n = y&7 (bijective; all 8
// n-blocks of an A-panel land on XCD x; blk%8==XCD proven in round 12).
// Grid 1280: 0..255 Q (MT=32) | 256..767 K (MT=64) | 768..1279 V (MT=64).
// V epilogue: transposed+rho-permuted [D][NC] (verified layout).
// ---------------------------------------------------------------------------
__global__ __launch_bounds__(256) void gemm_qkv_tiled(
    const short* __restrict__ Xq, const short* __restrict__ Xc,
    const short* __restrict__ Wq, const short* __restrict__ Wk,
    const short* __restrict__ Wv,
    const float* __restrict__ bq, const float* __restrict__ bk,
    const float* __restrict__ bv,
    short* __restrict__ Qout, short* __restrict__ Kout,
    short* __restrict__ VoutT)
{
    __shared__ __align__(16) short Ab[2][TBM * TPAD];   // 10240 B
    __shared__ __align__(16) short Bb[2][TBN * TPAD];   // 10240 B

    int tid = threadIdx.x;
    int wave = tid >> 6, lane = tid & 63;
    int quad = lane >> 4, l15 = lane & 15;

    int blk = blockIdx.x;
    const short *X, *W;
    const float* bias;
    short* outp;
    int bm, bn, vmode;
    {
        int local, mtdiv8;
        if (blk < 256)      { local = blk;       mtdiv8 = 4; }   // Q: MT=32
        else if (blk < 768) { local = blk - 256; mtdiv8 = 8; }   // K: MT=64
        else                { local = blk - 768; mtdiv8 = 8; }   // V: MT=64
        int x = local & 7, y = local >> 3;
        int m = x * mtdiv8 + (y >> 3);
        int n = y & 7;
        bm = m * TBM; bn = n * TBN;
    }
    if (blk < 256)      { X = Xq; W = Wq; bias = bq; outp = Qout;  vmode = 0; }
    else if (blk < 768) { X = Xc; W = Wk; bias = bk; outp = Kout;  vmode = 0; }
    else                { X = Xc; W = Wv; bias = bv; outp = VoutT; vmode = 1; }

    // staging maps: A 64x32 (1 short8/thread), B 64x32 (1 short8/thread)
    int ar = tid >> 2, ac = (tid & 3) * 8;
    int br = tid >> 2, bc = (tid & 3) * 8;
    const short* ag = X + (size_t)(bm + ar) * D + ac;
    const short* bg = W + (size_t)(bn + br) * D + bc;
    short* aw0 = &Ab[0][ar * TPAD + ac];
    short* aw1 = &Ab[1][ar * TPAD + ac];
    short* bw0 = &Bb[0][br * TPAD + bc];
    short* bw1 = &Bb[1][br * TPAD + bc];

    short8 ra, rb;

#define GLOAD(ks) {                                                            \
        ra = *(const short8*)(ag + (ks) * TBK);                                \
        rb = *(const short8*)(bg + (ks) * TBK); }
#define GDSW0 { *(short8*)aw0 = ra; *(short8*)bw0 = rb; }
#define GDSW1 { *(short8*)aw1 = ra; *(short8*)bw1 = rb; }

    float4v c00 = {0,0,0,0}, c01 = {0,0,0,0}, c02 = {0,0,0,0}, c03 = {0,0,0,0};

    // wave owns rows [wave*16, wave*16+16) of the A-tile, all 64 B-cols.
#define GCOMP(B)                                                               \
    {                                                                          \
        const short* abase = &Ab[B][(wave * 16 + l15) * TPAD + quad * 8];      \
        const short* bbase = &Bb[B][l15 * TPAD + quad * 8];                    \
        short8 a0 = *(const short8*)(abase);                                   \
        short8 b0 = *(const short8*)(bbase);                                   \
        short8 b1 = *(const short8*)(bbase + 16 * TPAD);                       \
        short8 b2 = *(const short8*)(bbase + 32 * TPAD);                       \
        short8 b3 = *(const short8*)(bbase + 48 * TPAD);                       \
        c00 = __builtin_amdgcn_mfma_f32_16x16x32_bf16(a0, b0, c00, 0, 0, 0);   \
        c01 = __builtin_amdgcn_mfma_f32_16x16x32_bf16(a0, b1, c01, 0, 0, 0);   \
        c02 = __builtin_amdgcn_mfma_f32_16x16x32_bf16(a0, b2, c02, 0, 0, 0);   \
        c03 = __builtin_amdgcn_mfma_f32_16x16x32_bf16(a0, b3, c03, 0, 0, 0);   \
    }

    GLOAD(0);
    GDSW0;
    GLOAD(1);
    __syncthreads();

    for (int t = 0; t < 14; t += 2) {
        GDSW1;
        GLOAD(t + 2);
        GCOMP(0);
        __syncthreads();
        GDSW0;
        GLOAD(t + 3);
        GCOMP(1);
        __syncthreads();
    }
    GDSW1;
    GCOMP(0);
    __syncthreads();
    GCOMP(1);

#undef GLOAD
#undef GDSW0
#undef GDSW1
#undef GCOMP

    float4v accs[4] = {c00, c01, c02, c03};
    if (vmode == 0) {
        int orow = bm + wave * 16 + quad * 4;
#pragma unroll
        for (int nf = 0; nf < 4; nf++) {
            int col = bn + nf * 16 + l15;
            float bb_ = bias[col];
#pragma unroll
            for (int r = 0; r < 4; r++)
                outp[(size_t)(orow + r) * D + col] = f2bf(accs[nf][r] + bb_);
        }
    } else {
        int orow = bm + wave * 16 + quad * 4;   // 4-aligned context base
        int a = (orow & 31) >> 2;
        int posb = (a < 4) ? (8 * a) : (8 * (a - 4) + 4);
        int cp = (orow & ~31) + posb;
#pragma unroll
        for (int nf = 0; nf < 4; nf++) {
            int col = bn + nf * 16 + l15;
            float bb_ = bias[col];
            short4v o;
#pragma unroll
            for (int r = 0; r < 4; r++) o[r] = f2bf(accs[nf][r] + bb_);
            *(short4v*)(outp + (size_t)col * NC + cp) = o;
        }
    }
}

// ---------------------------------------------------------------------------
// TILED output projection: Xf = Att @ Wo^T + bo + resid (f32 out).
// TBM=64 (grid 256 = 1/CU, was 128 = 0.5/CU) + XCD remap (MT=32).
// ---------------------------------------------------------------------------
__global__ __launch_bounds__(256) void gemm_out_tiled(
    const short* __restrict__ X, const short* __restrict__ W,
    const float* __restrict__ bias, const float* __restrict__ resid,
    float* __restrict__ out)
{
    __shared__ __align__(16) short Ab[2][TBM * TPAD];   // 10240 B
    __shared__ __align__(16) short Bb[2][TBN * TPAD];   // 10240 B

    int tid = threadIdx.x;
    int wave = tid >> 6, lane = tid & 63;
    int quad = lane >> 4, l15 = lane & 15;

    int blk = blockIdx.x;
    int x = blk & 7, y = blk >> 3;          // y in [0,32)
    int bm = (x * 4 + (y >> 3)) * TBM;      // MT=32
    int bn = (y & 7) * TBN;

    int ar = tid >> 2, ac = (tid & 3) * 8;
    int br = tid >> 2, bc = (tid & 3) * 8;
    const short* ag = X + (size_t)(bm + ar) * D + ac;
    const short* bg = W + (size_t)(bn + br) * D + bc;
    short* aw0 = &Ab[0][ar * TPAD + ac];
    short* aw1 = &Ab[1][ar * TPAD + ac];
    short* bw0 = &Bb[0][br * TPAD + bc];
    short* bw1 = &Bb[1][br * TPAD + bc];

    short8 ra, rb;

#define GLOAD(ks) {                                                            \
        ra = *(const short8*)(ag + (ks) * TBK);                                \
        rb = *(const short8*)(bg + (ks) * TBK); }
#define GDSW0 { *(short8*)aw0 = ra; *(short8*)bw0 = rb; }
#define GDSW1 { *(short8*)aw1 = ra; *(short8*)bw1 = rb; }

    float4v c00 = {0,0,0,0}, c01 = {0,0,0,0}, c02 = {0,0,0,0}, c03 = {0,0,0,0};

#define GCOMP(B)                                                               \
    {                                                                          \
        const short* abase = &Ab[B][(wave * 16 + l15) * TPAD + quad * 8];      \
        const short* bbase = &Bb[B][l15 * TPAD + quad * 8];                    \
        short8 a0 = *(const short8*)(abase);                                   \
        short8 b0 = *(const short8*)(bbase);                                   \
        short8 b1 = *(const short8*)(bbase + 16 * TPAD);                       \
        short8 b2 = *(const short8*)(bbase + 32 * TPAD);                       \
        short8 b3 = *(const short8*)(bbase + 48 * TPAD);                       \
        c00 = __builtin_amdgcn_mfma_f32_16x16x32_bf16(a0, b0, c00, 0, 0, 0);   \
        c01 = __builtin_amdgcn_mfma_f32_16x16x32_bf16(a0, b1, c01, 0, 0, 0);   \
        c02 = __builtin_amdgcn_mfma_f32_16x16x32_bf16(a0, b2, c02, 0, 0, 0);   \
        c03 = __builtin_amdgcn_mfma_f32_16x16x32_bf16(a0, b3, c03, 0, 0, 0);   \
    }

    GLOAD(0);
    GDSW0;
    GLOAD(1);
    __syncthreads();

    for (int t = 0; t < 14; t += 2) {
        GDSW1;
        GLOAD(t + 2);
        GCOMP(0);
        __syncthreads();
        GDSW0;
        GLOAD(t + 3);
        GCOMP(1);
        __syncthreads();
    }
    GDSW1;
    GCOMP(0);
    __syncthreads();
    GCOMP(1);

#undef GLOAD
#undef GDSW0
#undef GDSW1
#undef GCOMP

    float4v accs[4] = {c00, c01, c02, c03};
    int orow = bm + wave * 16 + quad * 4;
#pragma unroll
    for (int nf = 0; nf < 4; nf++) {
        int col = bn + nf * 16 + l15;
        float bb_ = bias[col];
#pragma unroll
        for (int r = 0; r < 4; r++)
            out[(size_t)(orow + r) * D + col] =
                accs[nf][r] + bb_ + resid[(size_t)(orow + r) * D + col];
    }
}

// Fallback: naive res GEMM writing f32 (used with separate layernorm_kernel).
__global__ __launch_bounds__(256) void gemm_bt_bias_res_f32(
    const short* __restrict__ X, const short* __restrict__ W,
    const float* __restrict__ bias, const float* __restrict__ resid,
    float* __restrict__ out, int M)
{
    int wave = threadIdx.x >> 6, lane = threadIdx.x & 63;
    int gt = blockIdx.x * 4 + wave;
    int tm = gt >> 3;
    int tg = gt & 7;
    if (tm >= (M >> 4)) return;
    int l15 = lane & 15, quad = lane >> 4;
    const short* xp = X + (tm * 16 + l15) * D + quad * 8;
    const short* wp = W + (tg * 64 + l15) * D + quad * 8;
    float4v a0 = {0,0,0,0}, a1 = {0,0,0,0}, a2 = {0,0,0,0}, a3 = {0,0,0,0};
#pragma unroll
    for (int k = 0; k < D; k += 32) {
        short8 a  = *(const short8*)(xp + k);
        short8 b0 = *(const short8*)(wp + k);
        short8 b1 = *(const short8*)(wp + 16 * D + k);
        short8 b2 = *(const short8*)(wp + 32 * D + k);
        short8 b3 = *(const short8*)(wp + 48 * D + k);
        a0 = __builtin_amdgcn_mfma_f32_16x16x32_bf16(a, b0, a0, 0, 0, 0);
        a1 = __builtin_amdgcn_mfma_f32_16x16x32_bf16(a, b1, a1, 0, 0, 0);
        a2 = __builtin_amdgcn_mfma_f32_16x16x32_bf16(a, b2, a2, 0, 0, 0);
        a3 = __builtin_amdgcn_mfma_f32_16x16x32_bf16(a, b3, a3, 0, 0, 0);
    }
    int orow = tm * 16 + quad * 4;
    float4v accs[4] = {a0, a1, a2, a3};
#pragma unroll
    for (int j = 0; j < 4; j++) {
        int col = tg * 64 + j * 16 + l15;
        float bv = bias[col];
#pragma unroll
        for (int r = 0; r < 4; r++) {
            int q = orow + r;
            out[q * D + col] = accs[j][r] + bv + resid[q * D + col];
        }
    }
}

// ---------------------------------------------------------------------------
// MFMA flash attention v10 (rounds 12/14 PASSED): v9 body + XCD 1D-grid
// swizzle (FETCH 35 -> 12.4 MB verified). UNCHANGED.
// NOTE: cc-from-global (v7/v8) produced NaN twice — do not reintroduce.
// ---------------------------------------------------------------------------
__global__ __launch_bounds__(256) void attn_mfma_split10(
    const short* __restrict__ Q, const short* __restrict__ K,
    const short* __restrict__ Vp,
    const float* __restrict__ qc, const float* __restrict__ cc,
    const float* __restrict__ log_scale, const float* __restrict__ bph,
    short* __restrict__ Opart, float* __restrict__ Lpart)
{
    __shared__ __align__(16) short Klds[2][32 * KP2];   // 17408 B
    __shared__ __align__(16) short Vlds[2][128 * VP];   // 20480 B
    __shared__ __align__(16) float ccl[512];            //  2048 B (256 ctx)

    int tid = threadIdx.x;
    int wave = tid >> 6, lane = tid & 63;

    // XCD swizzle decode
    int d = blockIdx.x;
    int s = (d & 7) * 128 + (d >> 3);
    int bx = s & 31;
    int by = (s >> 5) & 3;
    int bz = s >> 7;

    int h0 = by * 2;                    // head pair (h0, h0+1)
    int sp = bz;
    int q0 = bx * 64 + wave * 16;
    int quad = lane >> 4, l15 = lane & 15;
    int cbase = sp * CLEN;

    const float LOG2E = 1.4426950408889634f;
    const float escale = 0.125f * LOG2E;
    const float M0L = M0 * LOG2E;
    float ebase = __expf(log_scale[0]);
    float bh0 = ebase * bph[h0] * LOG2E;
    float bh1 = ebase * bph[h0 + 1] * LOG2E;

    const short* qp = Q + (q0 + l15) * D + h0 * HD + quad * 8;
    short8 qa0_0 = *(const short8*)(qp);
    short8 qa1_0 = *(const short8*)(qp + 32);
    short8 qa0_1 = *(const short8*)(qp + 64);
    short8 qa1_1 = *(const short8*)(qp + 96);

    float qx = qc[(q0 + l15) * 2];
    float qy = qc[(q0 + l15) * 2 + 1];

    float lacc0 = 0.f, lacc1 = 0.f;
    float4v O00 = {0,0,0,0}, O01 = {0,0,0,0}, O02 = {0,0,0,0}, O03 = {0,0,0,0};
    float4v O10 = {0,0,0,0}, O11 = {0,0,0,0}, O12 = {0,0,0,0}, O13 = {0,0,0,0};

    int kr_ = tid >> 3, kc_ = tid & 7;
    int vr_ = tid >> 2, vc_ = tid & 3;
    const short* kg  = K + (size_t)h0 * HD + kc_ * 8;            // +(c0+kr_)*D
    const short* vg0 = Vp + (size_t)(h0 * HD + vr_) * NC + vc_ * 8;       // +c0
    const short* vg1 = Vp + (size_t)(h0 * HD + 64 + vr_) * NC + vc_ * 8;  // +c0
    short* kw0a = &Klds[0][kr_ * KP2 + kc_ * 8];
    short* kw1a = &Klds[1][kr_ * KP2 + kc_ * 8];
    short* vw0a = &Vlds[0][vr_ * VP + vc_ * 8];
    short* vw0b = &Vlds[0][(64 + vr_) * VP + vc_ * 8];
    short* vw1a = &Vlds[1][vr_ * VP + vc_ * 8];
    short* vw1b = &Vlds[1][(64 + vr_) * VP + vc_ * 8];

    short8 rka, rkb, rva, rvb;   // staged regs for the next tile

#define LOADR(c0_)                                                             \
    {                                                                          \
        const short* kp_ = kg + (size_t)((c0_) + kr_) * D;                     \
        rka = *(const short8*)(kp_);                                           \
        rkb = *(const short8*)(kp_ + 64);                                      \
        rva = *(const short8*)(vg0 + (c0_));                                   \
        rvb = *(const short8*)(vg1 + (c0_));                                   \
    }

#define DSW0 { *(short8*)kw0a = rka; *(short8*)(kw0a + 64) = rkb;              \
               *(short8*)vw0a = rva; *(short8*)vw0b = rvb; }
#define DSW1 { *(short8*)kw1a = rka; *(short8*)(kw1a + 64) = rkb;              \
               *(short8*)vw1a = rva; *(short8*)vw1b = rvb; }

    const float2* ccp = (const float2*)ccl;

#define HEAD(hoff, QA0, QA1, BH, LACC, OA, OB, OC, OD)                         \
    {                                                                          \
        short8 k00 = *(const short8*)(kb + l15 * KP2 + (hoff) + quad * 8);     \
        short8 k01 = *(const short8*)(kb + l15 * KP2 + (hoff) + 32 + quad * 8);\
        short8 k10 = *(const short8*)(kb + (16 + l15) * KP2 + (hoff) + quad * 8);\
        short8 k11 = *(const short8*)(kb + (16 + l15) * KP2 + (hoff) + 32 + quad * 8);\
        float4v s0 = {0,0,0,0}, s1 = {0,0,0,0};                                \
        s0 = __builtin_amdgcn_mfma_f32_16x16x32_bf16(k00, QA0, s0, 0, 0, 0);   \
        s0 = __builtin_amdgcn_mfma_f32_16x16x32_bf16(k01, QA1, s0, 0, 0, 0);   \
        s1 = __builtin_amdgcn_mfma_f32_16x16x32_bf16(k10, QA0, s1, 0, 0, 0);   \
        s1 = __builtin_amdgcn_mfma_f32_16x16x32_bf16(k11, QA1, s1, 0, 0, 0);   \
        short8 v0 = *(const short8*)(vb + ((hoff) / 64 * 64 + l15) * VP + quad * 8);       \
        short8 v1 = *(const short8*)(vb + ((hoff) / 64 * 64 + 16 + l15) * VP + quad * 8);  \
        short8 v2 = *(const short8*)(vb + ((hoff) / 64 * 64 + 32 + l15) * VP + quad * 8);  \
        short8 v3 = *(const short8*)(vb + ((hoff) / 64 * 64 + 48 + l15) * VP + quad * 8);  \
        float p00 = exp2f(__fmaf_rn(s0[0], escale, __fmaf_rn(-(BH), dA0, -M0L)));\
        float p01 = exp2f(__fmaf_rn(s0[1], escale, __fmaf_rn(-(BH), dA1, -M0L)));\
        float p02 = exp2f(__fmaf_rn(s0[2], escale, __fmaf_rn(-(BH), dA2, -M0L)));\
        float p03 = exp2f(__fmaf_rn(s0[3], escale, __fmaf_rn(-(BH), dA3, -M0L)));\
        float p10 = exp2f(__fmaf_rn(s1[0], escale, __fmaf_rn(-(BH), dB0, -M0L)));\
        float p11 = exp2f(__fmaf_rn(s1[1], escale, __fmaf_rn(-(BH), dB1, -M0L)));\
        float p12 = exp2f(__fmaf_rn(s1[2], escale, __fmaf_rn(-(BH), dB2, -M0L)));\
        float p13 = exp2f(__fmaf_rn(s1[3], escale, __fmaf_rn(-(BH), dB3, -M0L)));\
        LACC += ((p00 + p01) + (p02 + p03)) + ((p10 + p11) + (p12 + p13));     \
        int4v pw;                                                              \
        pw.x = cvtpk(p00, p01); pw.y = cvtpk(p02, p03);                        \
        pw.z = cvtpk(p10, p11); pw.w = cvtpk(p12, p13);                        \
        short8 pa = __builtin_bit_cast(short8, pw);                            \
        OA = __builtin_amdgcn_mfma_f32_16x16x32_bf16(pa, v0, OA, 0, 0, 0);     \
        OB = __builtin_amdgcn_mfma_f32_16x16x32_bf16(pa, v1, OB, 0, 0, 0);     \
        OC = __builtin_amdgcn_mfma_f32_16x16x32_bf16(pa, v2, OC, 0, 0, 0);     \
        OD = __builtin_amdgcn_mfma_f32_16x16x32_bf16(pa, v3, OD, 0, 0, 0);     \
    }

#define COMPUTE_TILE(B, lo)                                                    \
    {                                                                          \
        const short* kb = &Klds[B][0];                                         \
        const short* vb = &Vlds[B][0];                                         \
        float2 ca0 = ccp[(lo) + 4 * quad + 0], cb0 = ccp[(lo) + 16 + 4 * quad + 0];\
        float2 ca1 = ccp[(lo) + 4 * quad + 1], cb1 = ccp[(lo) + 16 + 4 * quad + 1];\
        float2 ca2 = ccp[(lo) + 4 * quad + 2], cb2 = ccp[(lo) + 16 + 4 * quad + 2];\
        float2 ca3 = ccp[(lo) + 4 * quad + 3], cb3 = ccp[(lo) + 16 + 4 * quad + 3];\
        float dx, dy;                                                          \
        dx = qx - ca0.x; dy = qy - ca0.y;                                      \
        float dA0 = __builtin_amdgcn_sqrtf(__fmaf_rn(dx, dx, dy * dy));        \
        dx = qx - ca1.x; dy = qy - ca1.y;                                      \
        float dA1 = __builtin_amdgcn_sqrtf(__fmaf_rn(dx, dx, dy * dy));        \
        dx = qx - ca2.x; dy = qy - ca2.y;                                      \
        float dA2 = __builtin_amdgcn_sqrtf(__fmaf_rn(dx, dx, dy * dy));        \
        dx = qx - ca3.x; dy = qy - ca3.y;                                      \
        float dA3 = __builtin_amdgcn_sqrtf(__fmaf_rn(dx, dx, dy * dy));        \
        dx = qx - cb0.x; dy = qy - cb0.y;                                      \
        float dB0 = __builtin_amdgcn_sqrtf(__fmaf_rn(dx, dx, dy * dy));        \
        dx = qx - cb1.x; dy = qy - cb1.y;                                      \
        float dB1 = __builtin_amdgcn_sqrtf(__fmaf_rn(dx, dx, dy * dy));        \
        dx = qx - cb2.x; dy = qy - cb2.y;                                      \
        float dB2 = __builtin_amdgcn_sqrtf(__fmaf_rn(dx, dx, dy * dy));        \
        dx = qx - cb3.x; dy = qy - cb3.y;                                      \
        float dB3 = __builtin_amdgcn_sqrtf(__fmaf_rn(dx, dx, dy * dy));        \
        HEAD(0,  qa0_0, qa1_0, bh0, lacc0, O00, O01, O02, O03)                 \
        HEAD(64, qa0_1, qa1_1, bh1, lacc1, O10, O11, O12, O13)                 \
    }

    // ---- prologue: cc phase A (256 ctx) -> LDS, tile0 -> buf0, tile1 -> regs
    ((float2*)ccl)[tid] = ((const float2*)cc)[cbase + tid];
    LOADR(cbase);
    DSW0;
    LOADR(cbase + 32);
    __syncthreads();

    // ---- main loop: 16 tiles, 2x-unrolled (static buffer indices) ----
    for (int t = 0; t < NT - 2; t += 2) {
        int c0 = cbase + t * 32;
        if (t == 8) {
            ((float2*)ccl)[tid] = ((const float2*)cc)[cbase + 256 + tid];
            __syncthreads();
        }
        DSW1;
        LOADR(c0 + 64);
        COMPUTE_TILE(0, (t & 7) * 32);
        __syncthreads();
        DSW0;
        LOADR(c0 + 96);
        COMPUTE_TILE(1, (t & 7) * 32 + 32);
        __syncthreads();
    }
    DSW1;
    COMPUTE_TILE(0, 192);   // tile 14, rel (14-8)*32
    __syncthreads();
    COMPUTE_TILE(1, 224);   // tile 15, rel (15-8)*32

#undef LOADR
#undef DSW0
#undef DSW1
#undef HEAD
#undef COMPUTE_TILE

    lacc0 += __shfl_xor(lacc0, 16);
    lacc0 += __shfl_xor(lacc0, 32);
    lacc1 += __shfl_xor(lacc1, 16);
    lacc1 += __shfl_xor(lacc1, 32);

    long base0 = (long)(sp * H + h0) * NQ;
    long base1 = base0 + NQ;
    float4v Oarr0[4] = {O00, O01, O02, O03};
    float4v Oarr1[4] = {O10, O11, O12, O13};
#pragma unroll
    for (int t = 0; t < 4; t++) {
#pragma unroll
        for (int r = 0; r < 4; r++) {
            int q = q0 + quad * 4 + r;
            Opart[(base0 + q) * HD + t * 16 + l15] = f2bf(Oarr0[t][r]);
            Opart[(base1 + q) * HD + t * 16 + l15] = f2bf(Oarr1[t][r]);
        }
    }
    if (lane < 16) {
        Lpart[base0 + q0 + lane] = lacc0;
        Lpart[base1 + q0 + lane] = lacc1;
    }
}

// Plain-sum combine (all splits share fixed max M0) -> bf16 Att.
__global__ __launch_bounds__(256) void attn_combine(
    const short* __restrict__ Opart, const float* __restrict__ Lpart,
    short* __restrict__ Att)
{
    int id = blockIdx.x * 256 + threadIdx.x;   // over H*NQ*HD = 2^20
    int d = id & 63;
    int q = (id >> 6) & (NQ - 1);
    int h = id >> 17;
    float L = 0.f, acc = 0.f;
#pragma unroll
    for (int s = 0; s < SPLIT; s++) {
        long b = (long)(s * H + h) * NQ + q;
        L   += Lpart[b];
        acc += bf2f(Opart[b * HD + d]);
    }
    Att[q * D + h * HD + d] = f2bf(acc / L);
}

// ---------------------------------------------------------------------------
// Fallback single-pass attention (exact online softmax) if ws is too small.
// Expects V row-major [NC][D], unscaled Q.
// ---------------------------------------------------------------------------
__global__ __launch_bounds__(256) void attn_mfma(
    const short* __restrict__ Q, const short* __restrict__ K,
    const short* __restrict__ V,
    const float* __restrict__ qc, const float* __restrict__ cc,
    const float* __restrict__ log_scale, const float* __restrict__ bph,
    short* __restrict__ out)
{
    __shared__ short Vt[HD][48];
    __shared__ short P[4][16][48];
    int wave = threadIdx.x >> 6, lane = threadIdx.x & 63;
    int h = blockIdx.y;
    int q0 = blockIdx.x * 64 + wave * 16;
    int quad = lane >> 4, l15 = lane & 15;
    const float scale = 0.125f;
    float bh = __expf(log_scale[0]) * bph[h];
    const short* qp = Q + (q0 + l15) * D + h * HD + quad * 8;
    short8 qa0 = *(const short8*)(qp);
    short8 qa1 = *(const short8*)(qp + 32);
    float qx[4], qy[4];
#pragma unroll
    for (int r = 0; r < 4; r++) {
        int q = q0 + quad * 4 + r;
        qx[r] = qc[q * 2]; qy[r] = qc[q * 2 + 1];
    }
    float m[4], l[4];
    float4v O[4];
#pragma unroll
    for (int r = 0; r < 4; r++) { m[r] = -1e30f; l[r] = 0.f; }
#pragma unroll
    for (int t = 0; t < 4; t++) O[t] = (float4v){0.f, 0.f, 0.f, 0.f};
    for (int c0 = 0; c0 < NC; c0 += 32) {
        __syncthreads();
        {
            int c = threadIdx.x >> 3;
            int dblk = (threadIdx.x & 7) * 8;
            short8 vv = *(const short8*)(V + (c0 + c) * D + h * HD + dblk);
#pragma unroll
            for (int j = 0; j < 8; j++) Vt[dblk + j][c] = vv[j];
        }
        const short* kp0 = K + (c0 + l15) * D + h * HD + quad * 8;
        const short* kp1 = kp0 + 16 * D;
        short8 kb00 = *(const short8*)(kp0);
        short8 kb01 = *(const short8*)(kp0 + 32);
        short8 kb10 = *(const short8*)(kp1);
        short8 kb11 = *(const short8*)(kp1 + 32);
        float4v s0 = {0,0,0,0}, s1 = {0,0,0,0};
        s0 = __builtin_amdgcn_mfma_f32_16x16x32_bf16(qa0, kb00, s0, 0, 0, 0);
        s0 = __builtin_amdgcn_mfma_f32_16x16x32_bf16(qa1, kb01, s0, 0, 0, 0);
        s1 = __builtin_amdgcn_mfma_f32_16x16x32_bf16(qa0, kb10, s1, 0, 0, 0);
        s1 = __builtin_amdgcn_mfma_f32_16x16x32_bf16(qa1, kb11, s1, 0, 0, 0);
        int cA = c0 + l15, cB = cA + 16;
        float cxA = cc[cA * 2], cyA = cc[cA * 2 + 1];
        float cxB = cc[cB * 2], cyB = cc[cB * 2 + 1];
#pragma unroll
        for (int r = 0; r < 4; r++) {
            float dxA = qx[r] - cxA, dyA = qy[r] - cyA;
            float dxB = qx[r] - cxB, dyB = qy[r] - cyB;
            float v0 = s0[r] * scale - bh * sqrtf(dxA * dxA + dyA * dyA);
            float v1 = s1[r] * scale - bh * sqrtf(dxB * dxB + dyB * dyB);
            float mx = fmaxf(v0, v1);
#pragma unroll
            for (int off = 1; off < 16; off <<= 1) mx = fmaxf(mx, __shfl_xor(mx, off));
            float mnew = fmaxf(m[r], mx);
            float alpha = __expf(m[r] - mnew);
            float p0 = __expf(v0 - mnew);
            float p1 = __expf(v1 - mnew);
            float ps = p0 + p1;
#pragma unroll
            for (int off = 1; off < 16; off <<= 1) ps += __shfl_xor(ps, off);
            l[r] = l[r] * alpha + ps;
            m[r] = mnew;
#pragma unroll
            for (int t = 0; t < 4; t++) O[t][r] *= alpha;
            P[wave][quad * 4 + r][l15]      = f2bf(p0);
            P[wave][quad * 4 + r][16 + l15] = f2bf(p1);
        }
        __syncthreads();
        short8 pa = *(const short8*)(&P[wave][l15][quad * 8]);
#pragma unroll
        for (int t = 0; t < 4; t++) {
            short8 vb = *(const short8*)(&Vt[t * 16 + l15][quad * 8]);
            O[t] = __builtin_amdgcn_mfma_f32_16x16x32_bf16(pa, vb, O[t], 0, 0, 0);
        }
    }
#pragma unroll
    for (int t = 0; t < 4; t++) {
#pragma unroll
        for (int r = 0; r < 4; r++) {
            int q = q0 + quad * 4 + r;
            out[q * D + h * HD + t * 16 + l15] = f2bf(O[t][r] / l[r]);
        }
    }
}

// ---------------------------------------------------------------------------
// Row LayerNorm: one wave per row of 512 f32, output f32. Grid NQ/4 = 512.
// ---------------------------------------------------------------------------
__global__ __launch_bounds__(256) void layernorm_kernel(
    const float* __restrict__ X, const float* __restrict__ g,
    const float* __restrict__ b, float* __restrict__ out)
{
    int wave = threadIdx.x >> 6, lane = threadIdx.x & 63;
    int row = blockIdx.x * 4 + wave;
    const float* xp = X + row * D;
    float v[8];
    float s = 0.f;
#pragma unroll
    for (int i = 0; i < 8; i++) { v[i] = xp[lane + i * 64]; s += v[i]; }
#pragma unroll
    for (int off = 1; off < 64; off <<= 1) s += __shfl_xor(s, off);
    float mu = s * (1.f / D);
    float var = 0.f;
#pragma unroll
    for (int i = 0; i < 8; i++) { float d = v[i] - mu; var += d * d; }
#pragma unroll
    for (int off = 1; off < 64; off <<= 1) var += __shfl_xor(var, off);
    float rstd = rsqrtf(var * (1.f / D) + 1e-5f);
#pragma unroll
    for (int i = 0; i < 8; i++) {
        int c = lane + i * 64;
        out[row * D + c] = (v[i] - mu) * rstd * g[c] + b[c];
    }
}

extern "C" void kernel_launch(void* const* d_in, const int* in_sizes, int n_in,
                              void* d_out, int out_size, void* d_ws, size_t ws_size,
                              hipStream_t stream) {
    const float* query_repr     = (const float*)d_in[0];
    const float* context_repr   = (const float*)d_in[1];
    const float* query_coords   = (const float*)d_in[2];
    const float* context_coords = (const float*)d_in[3];
    const float* Wq = (const float*)d_in[4];
    const float* bq = (const float*)d_in[5];
    const float* Wk = (const float*)d_in[6];
    const float* bk = (const float*)d_in[7];
    const float* Wv = (const float*)d_in[8];
    const float* bv = (const float*)d_in[9];
    const float* Wo = (const float*)d_in[10];
    const float* bo = (const float*)d_in[11];
    const float* ln_g = (const float*)d_in[12];
    const float* ln_b = (const float*)d_in[13];
    const float* log_scale = (const float*)d_in[14];
    const float* bph = (const float*)d_in[15];

    short* ws = (short*)d_ws;
    short* Xq_bf = ws;                       // 1,048,576 shorts
    short* Xc_bf = Xq_bf + NQ * D;           // 2,097,152
    short* Wq_bf = Xc_bf + NC * D;           //   262,144 x4
    short* Wk_bf = Wq_bf + D * D;
    short* Wv_bf = Wk_bf + D * D;
    short* Wo_bf = Wv_bf + D * D;
    short* Qw  = Wo_bf + D * D;              // 1,048,576
    short* Kw  = Qw + NQ * D;                // 2,097,152
    short* Vw  = Kw + NC * D;                // 2,097,152 (Vp [D][NC] permuted)
    short* Att = Vw + NC * D;                // 1,048,576
    float* Xf  = (float*)(Att + NQ * D);     // 1,048,576 f32
    short* Opart = (short*)(Xf + NQ * D);    // SPLIT*H*NQ*HD bf16 = 16.8 MB
    float* Lpart = (float*)(Opart + (size_t)SPLIT * H * NQ * HD);  // 0.5 MB
    size_t ws_needed_split = ((char*)(Lpart + (size_t)SPLIT * H * NQ)) - (char*)d_ws;

    // 1. cast MFMA operands to bf16
    cast_all<<<dim3(4096), 256, 0, stream>>>(
        query_repr, context_repr, Wq, Wk, Wv, Wo, Xq_bf);

    if (ws_size >= ws_needed_split) {
        // 2. TILED Q+K+V projection (TBM=64, grid 1280 = 5 blocks/CU)
        gemm_qkv_tiled<<<dim3(1280), 256, 0, stream>>>(
            Xq_bf, Xc_bf, Wq_bf, Wk_bf, Wv_bf, bq, bk, bv, Qw, Kw, Vw);
        // 3. attention (v10: XCD-swizzled grid) + combine
        attn_mfma_split10<<<dim3(1024), 256, 0, stream>>>(
            Qw, Kw, Vw, query_coords, context_coords, log_scale, bph,
            Opart, Lpart);
        attn_combine<<<dim3(H * NQ * HD / 256), 256, 0, stream>>>(
            Opart, Lpart, Att);
        // 4. TILED output projection + residual (TBM=64, grid 256) -> Xf
        gemm_out_tiled<<<dim3(256), 256, 0, stream>>>(
            Att, Wo_bf, bo, query_repr, Xf);
        // 5. LayerNorm -> f32 output
        layernorm_kernel<<<dim3(NQ / 4), 256, 0, stream>>>(
            Xf, ln_g, ln_b, (float*)d_out);
    } else {
        gemm_bt_bias<<<dim3((NQ / 16) * 8 / 4), 256, 0, stream>>>(
            Xq_bf, Wq_bf, bq, Qw, NQ);
        gemm_bt_bias<<<dim3((NC / 16) * 8 / 4), 256, 0, stream>>>(
            Xc_bf, Wk_bf, bk, Kw, NC);
        gemm_bt_bias<<<dim3((NC / 16) * 8 / 4), 256, 0, stream>>>(
            Xc_bf, Wv_bf, bv, Vw, NC);
        attn_mfma<<<dim3(NQ / 64, H), 256, 0, stream>>>(
            Qw, Kw, Vw, query_coords, context_coords, log_scale, bph, Att);
        gemm_bt_bias_res_f32<<<dim3((NQ / 16) * 8 / 4), 256, 0, stream>>>(
            Att, Wo_bf, bo, query_repr, Xf, NQ);
        layernorm_kernel<<<dim3(NQ / 4), 256, 0, stream>>>(
            Xf, ln_g, ln_b, (float*)d_out);
    }
}